// Round 19
// baseline (537.202 us; speedup 1.0000x reference)
//
#include <hip/hip_runtime.h>
#include <math.h>

#define NN 50000
#define EE 800000
#define NEG 0.2f
#define NG (NN / 16)   // 3125 node groups

using f32x4  = __attribute__((ext_vector_type(4))) float;
using bf16x8 = __attribute__((ext_vector_type(8))) short;

__device__ __forceinline__ float lrelu(float x){ return x > 0.f ? x : NEG*x; }

__device__ __forceinline__ unsigned short f2b(float f){
    unsigned int u = __float_as_uint(f);
    return (unsigned short)((u + 0x7FFFu + ((u >> 16) & 1u)) >> 16);  // RNE
}
__device__ __forceinline__ float b2f(unsigned short h){
    return __uint_as_float(((unsigned int)h) << 16);
}
__device__ __forceinline__ void gld_lds16(const void* g, void* l){
    __builtin_amdgcn_global_load_lds(
        (const __attribute__((address_space(1))) unsigned int*)g,
        (__attribute__((address_space(3))) unsigned int*)l, 16, 0, 0);
}
__device__ __forceinline__ unsigned int cvtpk(float lo, float hi){
    unsigned int r;
    asm volatile("v_cvt_pk_bf16_f32 %0, %1, %2" : "=v"(r) : "v"(lo), "v"(hi));
    return r;
}

// ---------------------------------------------------------------------------
// Combined weight packer (1 dispatch). Fragment-order bf16.
// ---------------------------------------------------------------------------
__device__ __forceinline__ void pw_fusion_body(
    const float* __restrict__ W, unsigned short* __restrict__ out, int K, int u)
{
    int l = u & 63, chunk = (u >> 6) & 15, kc = u >> 10;
    int ct = chunk >> 2, r = chunk & 3;
    int c = ct * 16 + (l & 15);
    int kb = kc * 32 + (l >> 4) * 8;
    bf16x8 v;
#pragma unroll
    for (int j = 0; j < 8; ++j)
        v[j] = (short)f2b(W[((size_t)r * K + kb + j) * 64 + c]);
    *(bf16x8*)(out + (size_t)u * 8) = v;
}

__device__ __forceinline__ void pw_gemm_body(
    const float* __restrict__ W, unsigned short* __restrict__ out,
    int C, int PERM, int u)
{
    int NCH = C / 16;
    int l = u & 63, ch = (u >> 6) % NCH, kc = u / (64 * NCH);
    int c = ch * 16 + (l & 15);
    int kb = kc * 32 + (l >> 4) * 8;
    bf16x8 v;
#pragma unroll
    for (int j = 0; j < 8; ++j) {
        int k = kb + j;
        int ko = PERM ? ((k & 3) * 64 + (k >> 2)) : k;
        v[j] = (short)f2b(W[(size_t)ko * C + c]);
    }
    *(bf16x8*)(out + (size_t)u * 8) = v;
}

__global__ __launch_bounds__(256) void pack_all_w(
    const float* __restrict__ Wc, const float* __restrict__ Wt, const float* __restrict__ Wr,
    const float* __restrict__ W0, const float* __restrict__ W1,
    unsigned short* __restrict__ wpc, unsigned short* __restrict__ wpt,
    unsigned short* __restrict__ wpr, unsigned short* __restrict__ wp0,
    unsigned short* __restrict__ wp1)
{
    int b = blockIdx.x, t = threadIdx.x;
    if (b < 16)        pw_fusion_body(Wc, wpc, 129, b * 256 + t);
    else if (b < 80)   pw_fusion_body(Wt, wpt, 513, (b - 16) * 256 + t);
    else if (b < 144)  pw_fusion_body(Wr, wpr, 513, (b - 80) * 256 + t);
    else if (b < 152)  pw_gemm_body(W0, wp0, 256, 0, (b - 144) * 256 + t);
    else               pw_gemm_body(W1, wp1, 256, 1, (b - 152) * 256 + t);
}

// ---------------------------------------------------------------------------
// Fusion, rank-split; f32 features staged in FOUR 9-chunk phases (18.4KB LDS
// -> 8 blocks/CU vs 4). Width-16 gld_lds16, both-sides XOR swizzle (r18).
// accB reused for ht then hr so VGPR stays ~60 (prod *= accB at gcid 20).
// ---------------------------------------------------------------------------
__global__ __launch_bounds__(256) void fusion_mfma(
    const float* __restrict__ hc, const float* __restrict__ ht, const float* __restrict__ hr,
    const unsigned short* __restrict__ wpc, const unsigned short* __restrict__ wpt,
    const unsigned short* __restrict__ wpr,
    const float* __restrict__ Wc, const float* __restrict__ Wt, const float* __restrict__ Wr,
    const float* __restrict__ fw, const float* __restrict__ fb,
    unsigned short* __restrict__ h0b)
{
    __shared__ __align__(16) float lds[9 * 512];     // 18,432 B
    float* ldsx = lds;                               // aliased exchange (16KB)
    const int w = threadIdx.x >> 6, l = threadIdx.x & 63;
    const int G = blockIdx.x, nb = G * 16;
    const int c_lo = l & 15;

    // staging source geometry
    const int r0 = l >> 3;                       // row within 8-row half
    const int xs = ((l & 7) ^ (r0 & 7)) * 4;     // pre-swizzled dword offset

    // A-frag read geometry
    const int arow = l & 15;
    const int asl0 = ((l >> 4) * 2) ^ (arow & 7);
    const int asl1 = ((l >> 4) * 2 + 1) ^ (arow & 7);

    auto aread = [&](int slot) -> bf16x8 {
        const float* base = lds + slot * 512 + arow * 32;
        f32x4 a = *(const f32x4*)(base + asl0 * 4);
        f32x4 b = *(const f32x4*)(base + asl1 * 4);
        union { unsigned int wd[4]; bf16x8 v; } u;
        u.wd[0] = cvtpk(a[0], a[1]);
        u.wd[1] = cvtpk(a[2], a[3]);
        u.wd[2] = cvtpk(b[0], b[1]);
        u.wd[3] = cvtpk(b[2], b[3]);
        return u.v;
    };

    auto stage_chunk = [&](int gcid, int cid) {
        const float* F; int K, kc;
        if (gcid < 4)       { F = hc; K = 129; kc = gcid; }
        else if (gcid < 20) { F = ht; K = 513; kc = gcid - 4; }
        else                { F = hr; K = 513; kc = gcid - 20; }
#pragma unroll
        for (int i = 0; i < 2; ++i) {
            const float* g = F + (size_t)(nb + i * 8 + r0) * K + kc * 32 + xs;
            gld_lds16(g, lds + cid * 512 + i * 256);
        }
    };

    f32x4 prod[4], accB[4];
#pragma unroll
    for (int ct = 0; ct < 4; ++ct) {
        float wi = Wc[((size_t)w * 129 + 128) * 64 + ct * 16 + c_lo];
        prod[ct] = f32x4{wi, wi, wi, wi};
    }

#pragma unroll
    for (int p = 0; p < 4; ++p) {
        if (p) __syncthreads();                    // prior phase reads done
        stage_chunk(p * 9 + w, w);
        stage_chunk(p * 9 + w + 4, w + 4);
        if (w == 0) stage_chunk(p * 9 + 8, 8);
        __syncthreads();                           // staged (vmcnt drained)

#pragma unroll
        for (int s = 0; s < 9; ++s) {
            const int gcid = p * 9 + s;
            if (gcid == 4) {
#pragma unroll
                for (int ct = 0; ct < 4; ++ct) {
                    float wi = Wt[((size_t)w * 513 + 512) * 64 + ct * 16 + c_lo];
                    accB[ct] = f32x4{wi, wi, wi, wi};
                }
            }
            if (gcid == 20) {
#pragma unroll
                for (int ct = 0; ct < 4; ++ct) {
                    prod[ct] *= accB[ct];
                    float wi = Wr[((size_t)w * 513 + 512) * 64 + ct * 16 + c_lo];
                    accB[ct] = f32x4{wi, wi, wi, wi};
                }
            }
            bf16x8 af = aread(s);
            if (gcid < 4) {
                const unsigned short* wk = wpc + (size_t)gcid * 8192 + w * 512 + l * 8;
#pragma unroll
                for (int ct = 0; ct < 4; ++ct) {
                    bf16x8 bf = *(const bf16x8*)(wk + ct * 2048);
                    prod[ct] = __builtin_amdgcn_mfma_f32_16x16x32_bf16(af, bf, prod[ct], 0, 0, 0);
                }
            } else {
                const unsigned short* wk = (gcid < 20
                    ? wpt + (size_t)(gcid - 4) * 8192
                    : wpr + (size_t)(gcid - 20) * 8192) + w * 512 + l * 8;
#pragma unroll
                for (int ct = 0; ct < 4; ++ct) {
                    bf16x8 bf = *(const bf16x8*)(wk + ct * 2048);
                    accB[ct] = __builtin_amdgcn_mfma_f32_16x16x32_bf16(af, bf, accB[ct], 0, 0, 0);
                }
            }
        }
    }
    const float fww = fw[w];
#pragma unroll
    for (int ct = 0; ct < 4; ++ct) prod[ct] = prod[ct] * accB[ct] * fww;

    // ---- rank exchange (aliased LDS) + epilogue ----
    __syncthreads();
#pragma unroll
    for (int ct = 0; ct < 4; ++ct)
        *(f32x4*)&ldsx[((w * 4 + ct) * 64 + l) * 4] = prod[ct];
    __syncthreads();

    f32x4 s = *(const f32x4*)&ldsx[((0 * 4 + w) * 64 + l) * 4];
#pragma unroll
    for (int r = 1; r < 4; ++r)
        s += *(const f32x4*)&ldsx[((r * 4 + w) * 64 + l) * 4];

    const int c = w * 16 + c_lo;
    const float fbc = fb[c];
#pragma unroll
    for (int q = 0; q < 4; ++q) {
        int n = nb + (l >> 4) * 4 + q;
        float v = s[q] + fbc;
        v = v > 0.f ? v : expm1f(v);
        h0b[(size_t)n * 64 + c] = f2b(v);
    }
}

// ---------------------------------------------------------------------------
// feat GEMM with FUSED el/er epilogue. HEAD-MINOR output featb[n][d*4+h].
// ---------------------------------------------------------------------------
template<int K>
__global__ __launch_bounds__(256) void gemm_reg(
    const unsigned short* __restrict__ Ab, const unsigned short* __restrict__ wp,
    const float* __restrict__ al, const float* __restrict__ ar,
    unsigned short* __restrict__ featb,
    float* __restrict__ el, float* __restrict__ er)
{
    constexpr int NKC = K / 32;
    const int w = threadIdx.x >> 6, l = threadIdx.x & 63;
    const int nb = blockIdx.x * 16;

    f32x4 acc[4];
#pragma unroll
    for (int i = 0; i < 4; ++i) acc[i] = f32x4{0.f, 0.f, 0.f, 0.f};

    const unsigned short* abase = Ab + (size_t)(nb + (l & 15)) * K + (l >> 4) * 8;
    bf16x8 afs[NKC];
#pragma unroll
    for (int kc = 0; kc < NKC; ++kc)
        afs[kc] = *(const bf16x8*)(abase + kc * 32);

    bf16x8 bcur[4];
    {
        const unsigned short* wk = wp + (size_t)(0 * 16 + w * 4) * 512 + l * 8;
#pragma unroll
        for (int i = 0; i < 4; ++i) bcur[i] = *(const bf16x8*)(wk + i * 512);
    }
#pragma unroll
    for (int kc = 0; kc < NKC; ++kc) {
        bf16x8 bnxt[4];
        if (kc + 1 < NKC) {
            const unsigned short* wk = wp + ((size_t)(kc + 1) * 16 + w * 4) * 512 + l * 8;
#pragma unroll
            for (int i = 0; i < 4; ++i) bnxt[i] = *(const bf16x8*)(wk + i * 512);
        }
#pragma unroll
        for (int i = 0; i < 4; ++i)
            acc[i] = __builtin_amdgcn_mfma_f32_16x16x32_bf16(afs[kc], bcur[i], acc[i], 0, 0, 0);
        if (kc + 1 < NKC) {
#pragma unroll
            for (int i = 0; i < 4; ++i) bcur[i] = bnxt[i];
        }
    }

#pragma unroll
    for (int i = 0; i < 4; ++i) {
        int c = (w * 4 + i) * 16 + (l & 15);
        int dm = (c & 63) * 4 + (c >> 6);
#pragma unroll
        for (int q = 0; q < 4; ++q) {
            int n = nb + (l >> 4) * 4 + q;
            featb[(size_t)n * 256 + dm] = f2b(acc[i][q]);
        }
    }

    float pel[4] = {0.f, 0.f, 0.f, 0.f};
    float per_[4] = {0.f, 0.f, 0.f, 0.f};
#pragma unroll
    for (int i = 0; i < 4; ++i) {
        int d = i * 16 + (l & 15);
        float av = al[w * 64 + d];
        float rv = ar[w * 64 + d];
#pragma unroll
        for (int q = 0; q < 4; ++q) {
            pel[q] += acc[i][q] * av;
            per_[q] += acc[i][q] * rv;
        }
    }
#pragma unroll
    for (int off = 1; off <= 8; off <<= 1) {
#pragma unroll
        for (int q = 0; q < 4; ++q) {
            pel[q] += __shfl_xor(pel[q], off);
            per_[q] += __shfl_xor(per_[q], off);
        }
    }
    int qsel = l & 15;
    if (qsel < 4) {
        float ev = qsel == 0 ? pel[0] : qsel == 1 ? pel[1] : qsel == 2 ? pel[2] : pel[3];
        float rv = qsel == 0 ? per_[0] : qsel == 1 ? per_[1] : qsel == 2 ? per_[2] : per_[3];
        int n = nb + (l >> 4) * 4 + qsel;
        el[(size_t)n * 4 + w] = ev;
        er[(size_t)n * 4 + w] = rv;
    }
}

// ---------------------------------------------------------------------------
// CSR build (scan re-zeroes cnt for scatter)
// ---------------------------------------------------------------------------
__global__ void hist_kernel(const int* __restrict__ dst, int* __restrict__ cnt)
{
    int e = blockIdx.x * blockDim.x + threadIdx.x;
    if (e < EE) atomicAdd(&cnt[dst[e]], 1);
}

__global__ __launch_bounds__(1024) void scan_kernel(int* __restrict__ cnt, int* __restrict__ offs)
{
    __shared__ int tmp[1024];
    const int t = threadIdx.x;
    const int C = (NN + 1023) / 1024;
    int lo = t * C, hi = min(lo + C, NN);
    int s = 0;
    for (int i = lo; i < hi; ++i) s += cnt[i];
    tmp[t] = s;
    __syncthreads();
    for (int off = 1; off < 1024; off <<= 1) {
        int v = (t >= off) ? tmp[t - off] : 0;
        __syncthreads();
        tmp[t] += v;
        __syncthreads();
    }
    int run = (t == 0) ? 0 : tmp[t - 1];
    for (int i = lo; i < hi; ++i) { offs[i] = run; run += cnt[i]; cnt[i] = 0; }
    if (t == 1023) offs[NN] = tmp[1023];
}

__global__ void scatter_kernel(const int* __restrict__ dst, const int* __restrict__ offs,
                               int* __restrict__ cur, int* __restrict__ esort)
{
    int e = blockIdx.x * blockDim.x + threadIdx.x;
    if (e < EE) {
        int d = dst[e];
        int p = offs[d] + atomicAdd(&cur[d], 1);
        esort[p] = e;
    }
}

// ---------------------------------------------------------------------------
// gat_agg, register-cached softmax (deg<=64 fast path; lane owns one edge).
// ---------------------------------------------------------------------------
template <int RESID, int WATT, int WB16, int WF32>
__global__ __launch_bounds__(256) void gat_agg(
    const int* __restrict__ esort, const int* __restrict__ src, const int* __restrict__ offs,
    const unsigned short* __restrict__ featb,
    const float* __restrict__ el, const float* __restrict__ er,
    const unsigned short* __restrict__ residb, const float* __restrict__ bias,
    float* __restrict__ out, unsigned short* __restrict__ outb,
    float4* __restrict__ att)
{
    int n = (int)((blockIdx.x * (size_t)blockDim.x + threadIdx.x) >> 6);
    int lane = threadIdx.x & 63;
    if (n >= NN) return;
    const int s0 = offs[n], s1 = offs[n + 1], deg = s1 - s0;
    const float4 r4 = *(const float4*)(er + (size_t)n * 4);

    float a0 = 0.f, a1 = 0.f, a2 = 0.f, a3 = 0.f;
    float i0, i1, i2, i3;

    if (deg <= 64) {
        int p = s0 + lane;
        bool valid = p < s1;
        int e = valid ? esort[p] : 0;
        int sv = valid ? src[e] : 0;
        float v0 = -1e30f, v1 = -1e30f, v2 = -1e30f, v3 = -1e30f;
        if (valid) {
            float4 l4 = *(const float4*)(el + (size_t)sv * 4);
            v0 = lrelu(l4.x + r4.x); v1 = lrelu(l4.y + r4.y);
            v2 = lrelu(l4.z + r4.z); v3 = lrelu(l4.w + r4.w);
        }
        float m0 = v0, m1 = v1, m2 = v2, m3 = v3;
#pragma unroll
        for (int off = 32; off; off >>= 1) {
            m0 = fmaxf(m0, __shfl_xor(m0, off));
            m1 = fmaxf(m1, __shfl_xor(m1, off));
            m2 = fmaxf(m2, __shfl_xor(m2, off));
            m3 = fmaxf(m3, __shfl_xor(m3, off));
        }
        float e0 = valid ? expf(v0 - m0) : 0.f;
        float e1 = valid ? expf(v1 - m1) : 0.f;
        float e2 = valid ? expf(v2 - m2) : 0.f;
        float e3 = valid ? expf(v3 - m3) : 0.f;
        float z0 = e0, z1 = e1, z2 = e2, z3 = e3;
#pragma unroll
        for (int off = 32; off; off >>= 1) {
            z0 += __shfl_xor(z0, off);
            z1 += __shfl_xor(z1, off);
            z2 += __shfl_xor(z2, off);
            z3 += __shfl_xor(z3, off);
        }
        float j0 = z0 > 0.f ? 1.f / z0 : 0.f;
        float j1 = z1 > 0.f ? 1.f / z1 : 0.f;
        float j2 = z2 > 0.f ? 1.f / z2 : 0.f;
        float j3 = z3 > 0.f ? 1.f / z3 : 0.f;
        e0 *= j0; e1 *= j1; e2 *= j2; e3 *= j3;
        if (WATT && valid)
            att[e] = make_float4(e0, e1, e2, e3);
        for (int jj = 0; jj < deg; ++jj) {
            float w0 = __shfl(e0, jj), w1 = __shfl(e1, jj);
            float w2 = __shfl(e2, jj), w3 = __shfl(e3, jj);
            int s = __shfl(sv, jj);
            ushort4 f = *(const ushort4*)(featb + (size_t)s * 256 + lane * 4);
            a0 += w0 * b2f(f.x);
            a1 += w1 * b2f(f.y);
            a2 += w2 * b2f(f.z);
            a3 += w3 * b2f(f.w);
        }
        i0 = i1 = i2 = i3 = 1.f;
    } else {
        float m0 = -1e30f, m1 = -1e30f, m2 = -1e30f, m3 = -1e30f;
        for (int p = s0 + lane; p < s1; p += 64) {
            int s = src[esort[p]];
            float4 l4 = *(const float4*)(el + (size_t)s * 4);
            m0 = fmaxf(m0, lrelu(l4.x + r4.x));
            m1 = fmaxf(m1, lrelu(l4.y + r4.y));
            m2 = fmaxf(m2, lrelu(l4.z + r4.z));
            m3 = fmaxf(m3, lrelu(l4.w + r4.w));
        }
#pragma unroll
        for (int off = 32; off; off >>= 1) {
            m0 = fmaxf(m0, __shfl_xor(m0, off));
            m1 = fmaxf(m1, __shfl_xor(m1, off));
            m2 = fmaxf(m2, __shfl_xor(m2, off));
            m3 = fmaxf(m3, __shfl_xor(m3, off));
        }
        float z0 = 0.f, z1 = 0.f, z2 = 0.f, z3 = 0.f;
        for (int p = s0 + lane; p < s1; p += 64) {
            int s = src[esort[p]];
            float4 l4 = *(const float4*)(el + (size_t)s * 4);
            z0 += expf(lrelu(l4.x + r4.x) - m0);
            z1 += expf(lrelu(l4.y + r4.y) - m1);
            z2 += expf(lrelu(l4.z + r4.z) - m2);
            z3 += expf(lrelu(l4.w + r4.w) - m3);
        }
#pragma unroll
        for (int off = 32; off; off >>= 1) {
            z0 += __shfl_xor(z0, off);
            z1 += __shfl_xor(z1, off);
            z2 += __shfl_xor(z2, off);
            z3 += __shfl_xor(z3, off);
        }
        i0 = z0 > 0.f ? 1.f / z0 : 0.f;
        i1 = z1 > 0.f ? 1.f / z1 : 0.f;
        i2 = z2 > 0.f ? 1.f / z2 : 0.f;
        i3 = z3 > 0.f ? 1.f / z3 : 0.f;
        for (int p = s0; p < s1; ++p) {
            int e = esort[p];
            int s = src[e];
            float4 l4 = *(const float4*)(el + (size_t)s * 4);
            float w0 = expf(lrelu(l4.x + r4.x) - m0);
            float w1 = expf(lrelu(l4.y + r4.y) - m1);
            float w2 = expf(lrelu(l4.z + r4.z) - m2);
            float w3 = expf(lrelu(l4.w + r4.w) - m3);
            ushort4 f = *(const ushort4*)(featb + (size_t)s * 256 + lane * 4);
            a0 += w0 * b2f(f.x);
            a1 += w1 * b2f(f.y);
            a2 += w2 * b2f(f.z);
            a3 += w3 * b2f(f.w);
            if (WATT && lane == 0)
                att[e] = make_float4(w0 * i0, w1 * i1, w2 * i2, w3 * i3);
        }
    }

    float o0 = a0 * i0 + bias[lane];
    float o1 = a1 * i1 + bias[64 + lane];
    float o2 = a2 * i2 + bias[128 + lane];
    float o3 = a3 * i3 + bias[192 + lane];
    if (RESID) {
        ushort4 rp = *(const ushort4*)(residb + (size_t)n * 256 + lane * 4);
        o0 += b2f(rp.x); o1 += b2f(rp.y); o2 += b2f(rp.z); o3 += b2f(rp.w);
    }
    if (WF32) {
        float* op = out + (size_t)n * 256;
        op[lane] = o0;
        op[64 + lane] = o1;
        op[128 + lane] = o2;
        op[192 + lane] = o3;
    }
    if (WB16) {
        ushort4 ob;
        ob.x = f2b(o0); ob.y = f2b(o1); ob.z = f2b(o2); ob.w = f2b(o3);
        *(ushort4*)(outb + (size_t)n * 256 + lane * 4) = ob;
    }
}

// ---------------------------------------------------------------------------
extern "C" void kernel_launch(void* const* d_in, const int* in_sizes, int n_in,
                              void* d_out, int out_size, void* d_ws, size_t ws_size,
                              hipStream_t stream)
{
    const int*   src = (const int*)d_in[0];
    const int*   dst = (const int*)d_in[1];
    const float* hc  = (const float*)d_in[2];
    const float* ht  = (const float*)d_in[3];
    const float* hr  = (const float*)d_in[4];
    const float* Wc  = (const float*)d_in[5];
    const float* Wt  = (const float*)d_in[6];
    const float* Wr  = (const float*)d_in[7];
    const float* fw  = (const float*)d_in[8];
    const float* fb  = (const float*)d_in[9];
    const float* W0  = (const float*)d_in[10];
    const float* al0 = (const float*)d_in[11];
    const float* ar0 = (const float*)d_in[12];
    const float* b0  = (const float*)d_in[13];
    const float* W1  = (const float*)d_in[14];
    const float* al1 = (const float*)d_in[15];
    const float* ar1 = (const float*)d_in[16];
    const float* b1  = (const float*)d_in[17];

    // workspace layout (bytes); proven ws_size >= 63,553,792
    char* ws = (char*)d_ws;
    unsigned short* h0b   = (unsigned short*)(ws);               // N*64  bf16 :  6,400,000
    unsigned short* h1b   = (unsigned short*)(ws + 6400000);     // N*256 bf16 : 25,600,000 (head-minor)
    unsigned short* featb = (unsigned short*)(ws + 32000000);    // N*256 bf16 : 25,600,000 (head-minor)
    float* el    = (float*)(ws + 57600000);                      //    800,000
    float* er    = (float*)(ws + 58400000);                      //    800,000
    int*   cnt   = (int*)  (ws + 59200000);                      //    200,000
    int*   offs  = (int*)  (ws + 59400000);                      //    200,064 (padded)
    int*   esort = (int*)  (ws + 59600128);                      //  3,200,000
    unsigned short* wpc = (unsigned short*)(ws + 62800128);      //  4*16KB =  65,536
    unsigned short* wpt = (unsigned short*)(ws + 62865664);      // 16*16KB = 262,144
    unsigned short* wpr = (unsigned short*)(ws + 63127808);      // 16*16KB = 262,144
    unsigned short* wp0 = (unsigned short*)(ws + 63389952);      //  2*16KB =  32,768
    unsigned short* wp1 = (unsigned short*)(ws + 63422720);      //  8*16KB = 131,072
    if (ws_size < 63553792ull) return;                           // end of layout

    float* outh = (float*)d_out;                       // N*256 final h
    float4* atto = (float4*)(outh + (size_t)NN * 256); // E*4 att region

    // weight packing (single dispatch)
    pack_all_w<<<184, 256, 0, stream>>>(Wc, Wt, Wr, W0, W1, wpc, wpt, wpr, wp0, wp1);

    // trilinear fusion (rank-split, 4-phase 18.4KB staging -> 8 blocks/CU)
    fusion_mfma<<<NG, 256, 0, stream>>>(hc, ht, hr, wpc, wpt, wpr,
                                        Wc, Wt, Wr, fw, fb, h0b);

    // CSR by dst (scan re-zeroes cnt for scatter)
    hipMemsetAsync(cnt, 0, NN * sizeof(int), stream);
    hist_kernel<<<(EE + 255) / 256, 256, 0, stream>>>(dst, cnt);
    scan_kernel<<<1, 1024, 0, stream>>>(cnt, offs);
    scatter_kernel<<<(EE + 255) / 256, 256, 0, stream>>>(dst, offs, cnt, esort);

    // GAT layer 0: feat + el/er fused; softmax+agg in-register; bf16 h1b out
    gemm_reg<64><<<NG, 256, 0, stream>>>(h0b, wp0, al0, ar0, featb, el, er);
    gat_agg<0, 0, 1, 0><<<(NN * 64 + 255) / 256, 256, 0, stream>>>(
        esort, src, offs, featb, el, er, nullptr, b0, nullptr, h1b, nullptr);

    // GAT layer 1: residual from bf16 h1b; f32 out + attention (per-lane)
    gemm_reg<256><<<NG, 256, 0, stream>>>(h1b, wp1, al1, ar1, featb, el, er);
    gat_agg<1, 1, 0, 1><<<(NN * 64 + 255) / 256, 256, 0, stream>>>(
        esort, src, offs, featb, el, er, h1b, b1, outh, nullptr, atto);
}

// Round 20
// 522.950 us; speedup vs baseline: 1.0273x; 1.0273x over previous
//
#include <hip/hip_runtime.h>
#include <math.h>

#define NN 50000
#define EE 800000
#define NEG 0.2f
#define NG (NN / 16)   // 3125 node groups

using f32x4  = __attribute__((ext_vector_type(4))) float;
using bf16x8 = __attribute__((ext_vector_type(8))) short;

__device__ __forceinline__ float lrelu(float x){ return x > 0.f ? x : NEG*x; }

__device__ __forceinline__ unsigned short f2b(float f){
    unsigned int u = __float_as_uint(f);
    return (unsigned short)((u + 0x7FFFu + ((u >> 16) & 1u)) >> 16);  // RNE
}
__device__ __forceinline__ float b2f(unsigned short h){
    return __uint_as_float(((unsigned int)h) << 16);
}
__device__ __forceinline__ void gld_lds16(const void* g, void* l){
    __builtin_amdgcn_global_load_lds(
        (const __attribute__((address_space(1))) unsigned int*)g,
        (__attribute__((address_space(3))) unsigned int*)l, 16, 0, 0);
}
__device__ __forceinline__ unsigned int cvtpk(float lo, float hi){
    unsigned int r;
    asm volatile("v_cvt_pk_bf16_f32 %0, %1, %2" : "=v"(r) : "v"(lo), "v"(hi));
    return r;
}

// ---------------------------------------------------------------------------
// Combined weight packer (1 dispatch). Fragment-order bf16.
// ---------------------------------------------------------------------------
__device__ __forceinline__ void pw_fusion_body(
    const float* __restrict__ W, unsigned short* __restrict__ out, int K, int u)
{
    int l = u & 63, chunk = (u >> 6) & 15, kc = u >> 10;
    int ct = chunk >> 2, r = chunk & 3;
    int c = ct * 16 + (l & 15);
    int kb = kc * 32 + (l >> 4) * 8;
    bf16x8 v;
#pragma unroll
    for (int j = 0; j < 8; ++j)
        v[j] = (short)f2b(W[((size_t)r * K + kb + j) * 64 + c]);
    *(bf16x8*)(out + (size_t)u * 8) = v;
}

__device__ __forceinline__ void pw_gemm_body(
    const float* __restrict__ W, unsigned short* __restrict__ out,
    int C, int PERM, int u)
{
    int NCH = C / 16;
    int l = u & 63, ch = (u >> 6) % NCH, kc = u / (64 * NCH);
    int c = ch * 16 + (l & 15);
    int kb = kc * 32 + (l >> 4) * 8;
    bf16x8 v;
#pragma unroll
    for (int j = 0; j < 8; ++j) {
        int k = kb + j;
        int ko = PERM ? ((k & 3) * 64 + (k >> 2)) : k;
        v[j] = (short)f2b(W[(size_t)ko * C + c]);
    }
    *(bf16x8*)(out + (size_t)u * 8) = v;
}

__global__ __launch_bounds__(256) void pack_all_w(
    const float* __restrict__ Wc, const float* __restrict__ Wt, const float* __restrict__ Wr,
    const float* __restrict__ W0, const float* __restrict__ W1,
    unsigned short* __restrict__ wpc, unsigned short* __restrict__ wpt,
    unsigned short* __restrict__ wpr, unsigned short* __restrict__ wp0,
    unsigned short* __restrict__ wp1)
{
    int b = blockIdx.x, t = threadIdx.x;
    if (b < 16)        pw_fusion_body(Wc, wpc, 129, b * 256 + t);
    else if (b < 80)   pw_fusion_body(Wt, wpt, 513, (b - 16) * 256 + t);
    else if (b < 144)  pw_fusion_body(Wr, wpr, 513, (b - 80) * 256 + t);
    else if (b < 152)  pw_gemm_body(W0, wp0, 256, 0, (b - 144) * 256 + t);
    else               pw_gemm_body(W1, wp1, 256, 1, (b - 152) * 256 + t);
}

// ---------------------------------------------------------------------------
// Fusion (R18 2x18-phase staging) + INLINE layer-0 feat GEMM.
// Block G's rank-sum produces exactly the h0 rows gemm_reg<64> block G would
// consume -> fold it in: h0 tile (16x64 bf16, slot-XOR swizzled) written to
// LDS, then K=64 GEMM (2 chunks x 4 MFMA/wave, wp0) + featb/el/er epilogue.
// Deletes gemm_reg<64> dispatch and all h0b global traffic.
// ---------------------------------------------------------------------------
__global__ __launch_bounds__(256) void fusion_mfma(
    const float* __restrict__ hc, const float* __restrict__ ht, const float* __restrict__ hr,
    const unsigned short* __restrict__ wpc, const unsigned short* __restrict__ wpt,
    const unsigned short* __restrict__ wpr, const unsigned short* __restrict__ wp0,
    const float* __restrict__ Wc, const float* __restrict__ Wt, const float* __restrict__ Wr,
    const float* __restrict__ fw, const float* __restrict__ fb,
    const float* __restrict__ al0, const float* __restrict__ ar0,
    unsigned short* __restrict__ featb, float* __restrict__ el, float* __restrict__ er)
{
    __shared__ __align__(16) float lds[18 * 512];    // 36,864B (stage/exchange/h0)
    float* ldsx = lds;
    unsigned short* ldsh = (unsigned short*)lds;     // 2KB h0 tile (aliased)
    const int w = threadIdx.x >> 6, l = threadIdx.x & 63;
    const int G = blockIdx.x, nb = G * 16;
    const int c_lo = l & 15;

    // staging source geometry
    const int r0 = l >> 3;
    const int xs = ((l & 7) ^ (r0 & 7)) * 4;

    // A-frag read geometry (f32 staged chunks)
    const int arow = l & 15;
    const int asl0 = ((l >> 4) * 2) ^ (arow & 7);
    const int asl1 = ((l >> 4) * 2 + 1) ^ (arow & 7);

    auto aread = [&](int slot) -> bf16x8 {
        const float* base = lds + slot * 512 + arow * 32;
        f32x4 a = *(const f32x4*)(base + asl0 * 4);
        f32x4 b = *(const f32x4*)(base + asl1 * 4);
        union { unsigned int wd[4]; bf16x8 v; } u;
        u.wd[0] = cvtpk(a[0], a[1]);
        u.wd[1] = cvtpk(a[2], a[3]);
        u.wd[2] = cvtpk(b[0], b[1]);
        u.wd[3] = cvtpk(b[2], b[3]);
        return u.v;
    };

    auto stage_half = [&](int half) {
        for (int cid = w; cid < 18; cid += 4) {
            int gcid = half * 18 + cid;
            const float* F; int K, kc;
            if (gcid < 4)       { F = hc; K = 129; kc = gcid; }
            else if (gcid < 20) { F = ht; K = 513; kc = gcid - 4; }
            else                { F = hr; K = 513; kc = gcid - 20; }
#pragma unroll
            for (int i = 0; i < 2; ++i) {
                const float* g = F + (size_t)(nb + i * 8 + r0) * K + kc * 32 + xs;
                gld_lds16(g, lds + cid * 512 + i * 256);
            }
        }
    };

    f32x4 prod[4], accT[4], acc[4];

    // ---- half 0: hc g0-3, ht kc0-13 ----
    stage_half(0);
    __syncthreads();

#pragma unroll
    for (int ct = 0; ct < 4; ++ct) {
        float wi = Wc[((size_t)w * 129 + 128) * 64 + ct * 16 + c_lo];
        prod[ct] = f32x4{wi, wi, wi, wi};
    }
#pragma unroll
    for (int kc = 0; kc < 4; ++kc) {
        bf16x8 af = aread(kc);
        const unsigned short* wk = wpc + (size_t)kc * 8192 + w * 512 + l * 8;
#pragma unroll
        for (int ct = 0; ct < 4; ++ct) {
            bf16x8 bf = *(const bf16x8*)(wk + ct * 2048);
            prod[ct] = __builtin_amdgcn_mfma_f32_16x16x32_bf16(af, bf, prod[ct], 0, 0, 0);
        }
    }
#pragma unroll
    for (int ct = 0; ct < 4; ++ct) {
        float wi = Wt[((size_t)w * 513 + 512) * 64 + ct * 16 + c_lo];
        accT[ct] = f32x4{wi, wi, wi, wi};
    }
#pragma unroll
    for (int kc = 0; kc < 14; ++kc) {
        bf16x8 af = aread(4 + kc);
        const unsigned short* wk = wpt + (size_t)kc * 8192 + w * 512 + l * 8;
#pragma unroll
        for (int ct = 0; ct < 4; ++ct) {
            bf16x8 bf = *(const bf16x8*)(wk + ct * 2048);
            accT[ct] = __builtin_amdgcn_mfma_f32_16x16x32_bf16(af, bf, accT[ct], 0, 0, 0);
        }
    }

    // ---- half 1: ht kc14-15 (slots 0-1), hr kc0-15 (slots 2-17) ----
    __syncthreads();
    stage_half(1);
    __syncthreads();

#pragma unroll
    for (int kc = 14; kc < 16; ++kc) {
        bf16x8 af = aread(kc - 14);
        const unsigned short* wk = wpt + (size_t)kc * 8192 + w * 512 + l * 8;
#pragma unroll
        for (int ct = 0; ct < 4; ++ct) {
            bf16x8 bf = *(const bf16x8*)(wk + ct * 2048);
            accT[ct] = __builtin_amdgcn_mfma_f32_16x16x32_bf16(af, bf, accT[ct], 0, 0, 0);
        }
    }
#pragma unroll
    for (int ct = 0; ct < 4; ++ct) {
        prod[ct] *= accT[ct];
        float wi = Wr[((size_t)w * 513 + 512) * 64 + ct * 16 + c_lo];
        acc[ct] = f32x4{wi, wi, wi, wi};
    }
#pragma unroll
    for (int kc = 0; kc < 16; ++kc) {
        bf16x8 af = aread(2 + kc);
        const unsigned short* wk = wpr + (size_t)kc * 8192 + w * 512 + l * 8;
#pragma unroll
        for (int ct = 0; ct < 4; ++ct) {
            bf16x8 bf = *(const bf16x8*)(wk + ct * 2048);
            acc[ct] = __builtin_amdgcn_mfma_f32_16x16x32_bf16(af, bf, acc[ct], 0, 0, 0);
        }
    }
    const float fww = fw[w];
#pragma unroll
    for (int ct = 0; ct < 4; ++ct) prod[ct] = prod[ct] * acc[ct] * fww;

    // ---- rank exchange ----
    __syncthreads();
#pragma unroll
    for (int ct = 0; ct < 4; ++ct)
        *(f32x4*)&ldsx[((w * 4 + ct) * 64 + l) * 4] = prod[ct];
    __syncthreads();

    f32x4 s = *(const f32x4*)&ldsx[((0 * 4 + w) * 64 + l) * 4];
#pragma unroll
    for (int r = 1; r < 4; ++r)
        s += *(const f32x4*)&ldsx[((r * 4 + w) * 64 + l) * 4];

    // ---- ELU + write h0 tile (bf16, slot-XOR swizzled) ----
    const float fbc = fb[w * 16 + c_lo];
    __syncthreads();      // all rank-sum reads done before overwrite
#pragma unroll
    for (int q = 0; q < 4; ++q) {
        int row = (l >> 4) * 4 + q;
        int ccol = w * 16 + c_lo;
        float v = s[q] + fbc;
        v = v > 0.f ? v : expm1f(v);
        ldsh[row * 64 + (((ccol >> 3) ^ (row & 7)) << 3) + (ccol & 7)] = f2b(v);
    }
    __syncthreads();

    // ---- inline layer-0 feat GEMM (K=64) ----
    f32x4 a4[4];
#pragma unroll
    for (int i = 0; i < 4; ++i) a4[i] = f32x4{0.f, 0.f, 0.f, 0.f};
#pragma unroll
    for (int kc = 0; kc < 2; ++kc) {
        int sl = (kc * 4 + (l >> 4)) ^ (arow & 7);
        bf16x8 af = *(const bf16x8*)(ldsh + arow * 64 + sl * 8);
        const unsigned short* wk = wp0 + ((size_t)kc * 16 + w * 4) * 512 + l * 8;
#pragma unroll
        for (int i = 0; i < 4; ++i) {
            bf16x8 bf = *(const bf16x8*)(wk + i * 512);
            a4[i] = __builtin_amdgcn_mfma_f32_16x16x32_bf16(af, bf, a4[i], 0, 0, 0);
        }
    }

    // feat store (head-minor) + fused el/er for head h = w
#pragma unroll
    for (int i = 0; i < 4; ++i) {
        int c = (w * 4 + i) * 16 + c_lo;
        int dm = (c & 63) * 4 + (c >> 6);
#pragma unroll
        for (int q = 0; q < 4; ++q) {
            int n = nb + (l >> 4) * 4 + q;
            featb[(size_t)n * 256 + dm] = f2b(a4[i][q]);
        }
    }
    float pel[4] = {0.f, 0.f, 0.f, 0.f};
    float per_[4] = {0.f, 0.f, 0.f, 0.f};
#pragma unroll
    for (int i = 0; i < 4; ++i) {
        int d = i * 16 + c_lo;
        float av = al0[w * 64 + d];
        float rv = ar0[w * 64 + d];
#pragma unroll
        for (int q = 0; q < 4; ++q) {
            pel[q] += a4[i][q] * av;
            per_[q] += a4[i][q] * rv;
        }
    }
#pragma unroll
    for (int off = 1; off <= 8; off <<= 1) {
#pragma unroll
        for (int q = 0; q < 4; ++q) {
            pel[q] += __shfl_xor(pel[q], off);
            per_[q] += __shfl_xor(per_[q], off);
        }
    }
    int qsel = l & 15;
    if (qsel < 4) {
        float ev = qsel == 0 ? pel[0] : qsel == 1 ? pel[1] : qsel == 2 ? pel[2] : pel[3];
        float rv = qsel == 0 ? per_[0] : qsel == 1 ? per_[1] : qsel == 2 ? per_[2] : per_[3];
        int n = nb + (l >> 4) * 4 + qsel;
        el[(size_t)n * 4 + w] = ev;
        er[(size_t)n * 4 + w] = rv;
    }
}

// ---------------------------------------------------------------------------
// feat GEMM with FUSED el/er epilogue (layer 1 only). HEAD-MINOR output.
// ---------------------------------------------------------------------------
template<int K>
__global__ __launch_bounds__(256) void gemm_reg(
    const unsigned short* __restrict__ Ab, const unsigned short* __restrict__ wp,
    const float* __restrict__ al, const float* __restrict__ ar,
    unsigned short* __restrict__ featb,
    float* __restrict__ el, float* __restrict__ er)
{
    constexpr int NKC = K / 32;
    const int w = threadIdx.x >> 6, l = threadIdx.x & 63;
    const int nb = blockIdx.x * 16;

    f32x4 acc[4];
#pragma unroll
    for (int i = 0; i < 4; ++i) acc[i] = f32x4{0.f, 0.f, 0.f, 0.f};

    const unsigned short* abase = Ab + (size_t)(nb + (l & 15)) * K + (l >> 4) * 8;
    bf16x8 afs[NKC];
#pragma unroll
    for (int kc = 0; kc < NKC; ++kc)
        afs[kc] = *(const bf16x8*)(abase + kc * 32);

    bf16x8 bcur[4];
    {
        const unsigned short* wk = wp + (size_t)(0 * 16 + w * 4) * 512 + l * 8;
#pragma unroll
        for (int i = 0; i < 4; ++i) bcur[i] = *(const bf16x8*)(wk + i * 512);
    }
#pragma unroll
    for (int kc = 0; kc < NKC; ++kc) {
        bf16x8 bnxt[4];
        if (kc + 1 < NKC) {
            const unsigned short* wk = wp + ((size_t)(kc + 1) * 16 + w * 4) * 512 + l * 8;
#pragma unroll
            for (int i = 0; i < 4; ++i) bnxt[i] = *(const bf16x8*)(wk + i * 512);
        }
#pragma unroll
        for (int i = 0; i < 4; ++i)
            acc[i] = __builtin_amdgcn_mfma_f32_16x16x32_bf16(afs[kc], bcur[i], acc[i], 0, 0, 0);
        if (kc + 1 < NKC) {
#pragma unroll
            for (int i = 0; i < 4; ++i) bcur[i] = bnxt[i];
        }
    }

#pragma unroll
    for (int i = 0; i < 4; ++i) {
        int c = (w * 4 + i) * 16 + (l & 15);
        int dm = (c & 63) * 4 + (c >> 6);
#pragma unroll
        for (int q = 0; q < 4; ++q) {
            int n = nb + (l >> 4) * 4 + q;
            featb[(size_t)n * 256 + dm] = f2b(acc[i][q]);
        }
    }

    float pel[4] = {0.f, 0.f, 0.f, 0.f};
    float per_[4] = {0.f, 0.f, 0.f, 0.f};
#pragma unroll
    for (int i = 0; i < 4; ++i) {
        int d = i * 16 + (l & 15);
        float av = al[w * 64 + d];
        float rv = ar[w * 64 + d];
#pragma unroll
        for (int q = 0; q < 4; ++q) {
            pel[q] += acc[i][q] * av;
            per_[q] += acc[i][q] * rv;
        }
    }
#pragma unroll
    for (int off = 1; off <= 8; off <<= 1) {
#pragma unroll
        for (int q = 0; q < 4; ++q) {
            pel[q] += __shfl_xor(pel[q], off);
            per_[q] += __shfl_xor(per_[q], off);
        }
    }
    int qsel = l & 15;
    if (qsel < 4) {
        float ev = qsel == 0 ? pel[0] : qsel == 1 ? pel[1] : qsel == 2 ? pel[2] : pel[3];
        float rv = qsel == 0 ? per_[0] : qsel == 1 ? per_[1] : qsel == 2 ? per_[2] : per_[3];
        int n = nb + (l >> 4) * 4 + qsel;
        el[(size_t)n * 4 + w] = ev;
        er[(size_t)n * 4 + w] = rv;
    }
}

// ---------------------------------------------------------------------------
// CSR build (scan re-zeroes cnt for scatter)
// ---------------------------------------------------------------------------
__global__ void hist_kernel(const int* __restrict__ dst, int* __restrict__ cnt)
{
    int e = blockIdx.x * blockDim.x + threadIdx.x;
    if (e < EE) atomicAdd(&cnt[dst[e]], 1);
}

__global__ __launch_bounds__(1024) void scan_kernel(int* __restrict__ cnt, int* __restrict__ offs)
{
    __shared__ int tmp[1024];
    const int t = threadIdx.x;
    const int C = (NN + 1023) / 1024;
    int lo = t * C, hi = min(lo + C, NN);
    int s = 0;
    for (int i = lo; i < hi; ++i) s += cnt[i];
    tmp[t] = s;
    __syncthreads();
    for (int off = 1; off < 1024; off <<= 1) {
        int v = (t >= off) ? tmp[t - off] : 0;
        __syncthreads();
        tmp[t] += v;
        __syncthreads();
    }
    int run = (t == 0) ? 0 : tmp[t - 1];
    for (int i = lo; i < hi; ++i) { offs[i] = run; run += cnt[i]; cnt[i] = 0; }
    if (t == 1023) offs[NN] = tmp[1023];
}

__global__ void scatter_kernel(const int* __restrict__ dst, const int* __restrict__ offs,
                               int* __restrict__ cur, int* __restrict__ esort)
{
    int e = blockIdx.x * blockDim.x + threadIdx.x;
    if (e < EE) {
        int d = dst[e];
        int p = offs[d] + atomicAdd(&cur[d], 1);
        esort[p] = e;
    }
}

// ---------------------------------------------------------------------------
// gat_agg, register-cached softmax (deg<=64 fast path; lane owns one edge).
// ---------------------------------------------------------------------------
template <int RESID, int WATT, int WB16, int WF32>
__global__ __launch_bounds__(256) void gat_agg(
    const int* __restrict__ esort, const int* __restrict__ src, const int* __restrict__ offs,
    const unsigned short* __restrict__ featb,
    const float* __restrict__ el, const float* __restrict__ er,
    const unsigned short* __restrict__ residb, const float* __restrict__ bias,
    float* __restrict__ out, unsigned short* __restrict__ outb,
    float4* __restrict__ att)
{
    int n = (int)((blockIdx.x * (size_t)blockDim.x + threadIdx.x) >> 6);
    int lane = threadIdx.x & 63;
    if (n >= NN) return;
    const int s0 = offs[n], s1 = offs[n + 1], deg = s1 - s0;
    const float4 r4 = *(const float4*)(er + (size_t)n * 4);

    float a0 = 0.f, a1 = 0.f, a2 = 0.f, a3 = 0.f;
    float i0, i1, i2, i3;

    if (deg <= 64) {
        int p = s0 + lane;
        bool valid = p < s1;
        int e = valid ? esort[p] : 0;
        int sv = valid ? src[e] : 0;
        float v0 = -1e30f, v1 = -1e30f, v2 = -1e30f, v3 = -1e30f;
        if (valid) {
            float4 l4 = *(const float4*)(el + (size_t)sv * 4);
            v0 = lrelu(l4.x + r4.x); v1 = lrelu(l4.y + r4.y);
            v2 = lrelu(l4.z + r4.z); v3 = lrelu(l4.w + r4.w);
        }
        float m0 = v0, m1 = v1, m2 = v2, m3 = v3;
#pragma unroll
        for (int off = 32; off; off >>= 1) {
            m0 = fmaxf(m0, __shfl_xor(m0, off));
            m1 = fmaxf(m1, __shfl_xor(m1, off));
            m2 = fmaxf(m2, __shfl_xor(m2, off));
            m3 = fmaxf(m3, __shfl_xor(m3, off));
        }
        float e0 = valid ? expf(v0 - m0) : 0.f;
        float e1 = valid ? expf(v1 - m1) : 0.f;
        float e2 = valid ? expf(v2 - m2) : 0.f;
        float e3 = valid ? expf(v3 - m3) : 0.f;
        float z0 = e0, z1 = e1, z2 = e2, z3 = e3;
#pragma unroll
        for (int off = 32; off; off >>= 1) {
            z0 += __shfl_xor(z0, off);
            z1 += __shfl_xor(z1, off);
            z2 += __shfl_xor(z2, off);
            z3 += __shfl_xor(z3, off);
        }
        float j0 = z0 > 0.f ? 1.f / z0 : 0.f;
        float j1 = z1 > 0.f ? 1.f / z1 : 0.f;
        float j2 = z2 > 0.f ? 1.f / z2 : 0.f;
        float j3 = z3 > 0.f ? 1.f / z3 : 0.f;
        e0 *= j0; e1 *= j1; e2 *= j2; e3 *= j3;
        if (WATT && valid)
            att[e] = make_float4(e0, e1, e2, e3);
        for (int jj = 0; jj < deg; ++jj) {
            float w0 = __shfl(e0, jj), w1 = __shfl(e1, jj);
            float w2 = __shfl(e2, jj), w3 = __shfl(e3, jj);
            int s = __shfl(sv, jj);
            ushort4 f = *(const ushort4*)(featb + (size_t)s * 256 + lane * 4);
            a0 += w0 * b2f(f.x);
            a1 += w1 * b2f(f.y);
            a2 += w2 * b2f(f.z);
            a3 += w3 * b2f(f.w);
        }
        i0 = i1 = i2 = i3 = 1.f;
    } else {
        float m0 = -1e30f, m1 = -1e30f, m2 = -1e30f, m3 = -1e30f;
        for (int p = s0 + lane; p < s1; p += 64) {
            int s = src[esort[p]];
            float4 l4 = *(const float4*)(el + (size_t)s * 4);
            m0 = fmaxf(m0, lrelu(l4.x + r4.x));
            m1 = fmaxf(m1, lrelu(l4.y + r4.y));
            m2 = fmaxf(m2, lrelu(l4.z + r4.z));
            m3 = fmaxf(m3, lrelu(l4.w + r4.w));
        }
#pragma unroll
        for (int off = 32; off; off >>= 1) {
            m0 = fmaxf(m0, __shfl_xor(m0, off));
            m1 = fmaxf(m1, __shfl_xor(m1, off));
            m2 = fmaxf(m2, __shfl_xor(m2, off));
            m3 = fmaxf(m3, __shfl_xor(m3, off));
        }
        float z0 = 0.f, z1 = 0.f, z2 = 0.f, z3 = 0.f;
        for (int p = s0 + lane; p < s1; p += 64) {
            int s = src[esort[p]];
            float4 l4 = *(const float4*)(el + (size_t)s * 4);
            z0 += expf(lrelu(l4.x + r4.x) - m0);
            z1 += expf(lrelu(l4.y + r4.y) - m1);
            z2 += expf(lrelu(l4.z + r4.z) - m2);
            z3 += expf(lrelu(l4.w + r4.w) - m3);
        }
#pragma unroll
        for (int off = 32; off; off >>= 1) {
            z0 += __shfl_xor(z0, off);
            z1 += __shfl_xor(z1, off);
            z2 += __shfl_xor(z2, off);
            z3 += __shfl_xor(z3, off);
        }
        i0 = z0 > 0.f ? 1.f / z0 : 0.f;
        i1 = z1 > 0.f ? 1.f / z1 : 0.f;
        i2 = z2 > 0.f ? 1.f / z2 : 0.f;
        i3 = z3 > 0.f ? 1.f / z3 : 0.f;
        for (int p = s0; p < s1; ++p) {
            int e = esort[p];
            int s = src[e];
            float4 l4 = *(const float4*)(el + (size_t)s * 4);
            float w0 = expf(lrelu(l4.x + r4.x) - m0);
            float w1 = expf(lrelu(l4.y + r4.y) - m1);
            float w2 = expf(lrelu(l4.z + r4.z) - m2);
            float w3 = expf(lrelu(l4.w + r4.w) - m3);
            ushort4 f = *(const ushort4*)(featb + (size_t)s * 256 + lane * 4);
            a0 += w0 * b2f(f.x);
            a1 += w1 * b2f(f.y);
            a2 += w2 * b2f(f.z);
            a3 += w3 * b2f(f.w);
            if (WATT && lane == 0)
                att[e] = make_float4(w0 * i0, w1 * i1, w2 * i2, w3 * i3);
        }
    }

    float o0 = a0 * i0 + bias[lane];
    float o1 = a1 * i1 + bias[64 + lane];
    float o2 = a2 * i2 + bias[128 + lane];
    float o3 = a3 * i3 + bias[192 + lane];
    if (RESID) {
        ushort4 rp = *(const ushort4*)(residb + (size_t)n * 256 + lane * 4);
        o0 += b2f(rp.x); o1 += b2f(rp.y); o2 += b2f(rp.z); o3 += b2f(rp.w);
    }
    if (WF32) {
        float* op = out + (size_t)n * 256;
        op[lane] = o0;
        op[64 + lane] = o1;
        op[128 + lane] = o2;
        op[192 + lane] = o3;
    }
    if (WB16) {
        ushort4 ob;
        ob.x = f2b(o0); ob.y = f2b(o1); ob.z = f2b(o2); ob.w = f2b(o3);
        *(ushort4*)(outb + (size_t)n * 256 + lane * 4) = ob;
    }
}

// ---------------------------------------------------------------------------
extern "C" void kernel_launch(void* const* d_in, const int* in_sizes, int n_in,
                              void* d_out, int out_size, void* d_ws, size_t ws_size,
                              hipStream_t stream)
{
    const int*   src = (const int*)d_in[0];
    const int*   dst = (const int*)d_in[1];
    const float* hc  = (const float*)d_in[2];
    const float* ht  = (const float*)d_in[3];
    const float* hr  = (const float*)d_in[4];
    const float* Wc  = (const float*)d_in[5];
    const float* Wt  = (const float*)d_in[6];
    const float* Wr  = (const float*)d_in[7];
    const float* fw  = (const float*)d_in[8];
    const float* fb  = (const float*)d_in[9];
    const float* W0  = (const float*)d_in[10];
    const float* al0 = (const float*)d_in[11];
    const float* ar0 = (const float*)d_in[12];
    const float* b0  = (const float*)d_in[13];
    const float* W1  = (const float*)d_in[14];
    const float* al1 = (const float*)d_in[15];
    const float* ar1 = (const float*)d_in[16];
    const float* b1  = (const float*)d_in[17];

    // workspace layout (bytes); proven ws_size >= 63,553,792
    char* ws = (char*)d_ws;
    unsigned short* h1b   = (unsigned short*)(ws + 6400000);     // N*256 bf16 (head-minor)
    unsigned short* featb = (unsigned short*)(ws + 32000000);    // N*256 bf16 (head-minor)
    float* el    = (float*)(ws + 57600000);                      //    800,000
    float* er    = (float*)(ws + 58400000);                      //    800,000
    int*   cnt   = (int*)  (ws + 59200000);                      //    200,000
    int*   offs  = (int*)  (ws + 59400000);                      //    200,064 (padded)
    int*   esort = (int*)  (ws + 59600128);                      //  3,200,000
    unsigned short* wpc = (unsigned short*)(ws + 62800128);      //  4*16KB
    unsigned short* wpt = (unsigned short*)(ws + 62865664);      // 16*16KB
    unsigned short* wpr = (unsigned short*)(ws + 63127808);      // 16*16KB
    unsigned short* wp0 = (unsigned short*)(ws + 63389952);      //  2*16KB
    unsigned short* wp1 = (unsigned short*)(ws + 63422720);      //  8*16KB
    if (ws_size < 63553792ull) return;                           // end of layout

    float* outh = (float*)d_out;                       // N*256 final h
    float4* atto = (float4*)(outh + (size_t)NN * 256); // E*4 att region

    // weight packing (single dispatch)
    pack_all_w<<<184, 256, 0, stream>>>(Wc, Wt, Wr, W0, W1, wpc, wpt, wpr, wp0, wp1);

    // trilinear fusion + inline layer-0 feat GEMM (featb/el/er out; no h0b)
    fusion_mfma<<<NG, 256, 0, stream>>>(hc, ht, hr, wpc, wpt, wpr, wp0,
                                        Wc, Wt, Wr, fw, fb, al0, ar0,
                                        featb, el, er);

    // CSR by dst (scan re-zeroes cnt for scatter)
    hipMemsetAsync(cnt, 0, NN * sizeof(int), stream);
    hist_kernel<<<(EE + 255) / 256, 256, 0, stream>>>(dst, cnt);
    scan_kernel<<<1, 1024, 0, stream>>>(cnt, offs);
    scatter_kernel<<<(EE + 255) / 256, 256, 0, stream>>>(dst, offs, cnt, esort);

    // GAT layer 0: softmax+agg in-register; bf16 h1b out
    gat_agg<0, 0, 1, 0><<<(NN * 64 + 255) / 256, 256, 0, stream>>>(
        esort, src, offs, featb, el, er, nullptr, b0, nullptr, h1b, nullptr);

    // GAT layer 1: feat + el/er fused; residual from bf16 h1b; f32 out + att
    gemm_reg<256><<<NG, 256, 0, stream>>>(h1b, wp1, al1, ar1, featb, el, er);
    gat_agg<1, 1, 0, 1><<<(NN * 64 + 255) / 256, 256, 0, stream>>>(
        esort, src, offs, featb, el, er, h1b, b1, outh, nullptr, atto);
}

// Round 21
// 511.722 us; speedup vs baseline: 1.0498x; 1.0219x over previous
//
#include <hip/hip_runtime.h>
#include <math.h>

#define NN 50000
#define EE 800000
#define NEG 0.2f
#define NG (NN / 16)   // 3125 node groups

using f32x4  = __attribute__((ext_vector_type(4))) float;
using bf16x8 = __attribute__((ext_vector_type(8))) short;

__device__ __forceinline__ float lrelu(float x){ return x > 0.f ? x : NEG*x; }

__device__ __forceinline__ unsigned short f2b(float f){
    unsigned int u = __float_as_uint(f);
    return (unsigned short)((u + 0x7FFFu + ((u >> 16) & 1u)) >> 16);  // RNE
}
__device__ __forceinline__ float b2f(unsigned short h){
    return __uint_as_float(((unsigned int)h) << 16);
}
__device__ __forceinline__ void gld_lds16(const void* g, void* l){
    __builtin_amdgcn_global_load_lds(
        (const __attribute__((address_space(1))) unsigned int*)g,
        (__attribute__((address_space(3))) unsigned int*)l, 16, 0, 0);
}
__device__ __forceinline__ unsigned int cvtpk(float lo, float hi){
    unsigned int r;
    asm volatile("v_cvt_pk_bf16_f32 %0, %1, %2" : "=v"(r) : "v"(lo), "v"(hi));
    return r;
}

// ---------------------------------------------------------------------------
// Combined weight packer + cnt zeroing (1 dispatch). Fragment-order bf16.
// ---------------------------------------------------------------------------
__device__ __forceinline__ void pw_fusion_body(
    const float* __restrict__ W, unsigned short* __restrict__ out, int K, int u)
{
    int l = u & 63, chunk = (u >> 6) & 15, kc = u >> 10;
    int ct = chunk >> 2, r = chunk & 3;
    int c = ct * 16 + (l & 15);
    int kb = kc * 32 + (l >> 4) * 8;
    bf16x8 v;
#pragma unroll
    for (int j = 0; j < 8; ++j)
        v[j] = (short)f2b(W[((size_t)r * K + kb + j) * 64 + c]);
    *(bf16x8*)(out + (size_t)u * 8) = v;
}

__device__ __forceinline__ void pw_gemm_body(
    const float* __restrict__ W, unsigned short* __restrict__ out,
    int C, int PERM, int u)
{
    int NCH = C / 16;
    int l = u & 63, ch = (u >> 6) % NCH, kc = u / (64 * NCH);
    int c = ch * 16 + (l & 15);
    int kb = kc * 32 + (l >> 4) * 8;
    bf16x8 v;
#pragma unroll
    for (int j = 0; j < 8; ++j) {
        int k = kb + j;
        int ko = PERM ? ((k & 3) * 64 + (k >> 2)) : k;
        v[j] = (short)f2b(W[(size_t)ko * C + c]);
    }
    *(bf16x8*)(out + (size_t)u * 8) = v;
}

__global__ __launch_bounds__(256) void pack_all_w(
    const float* __restrict__ Wc, const float* __restrict__ Wt, const float* __restrict__ Wr,
    const float* __restrict__ W0, const float* __restrict__ W1,
    unsigned short* __restrict__ wpc, unsigned short* __restrict__ wpt,
    unsigned short* __restrict__ wpr, unsigned short* __restrict__ wp0,
    unsigned short* __restrict__ wp1, int* __restrict__ cnt)
{
    int b = blockIdx.x, t = threadIdx.x;
    if (b < 16)        pw_fusion_body(Wc, wpc, 129, b * 256 + t);
    else if (b < 80)   pw_fusion_body(Wt, wpt, 513, (b - 16) * 256 + t);
    else if (b < 144)  pw_fusion_body(Wr, wpr, 513, (b - 80) * 256 + t);
    else if (b < 152)  pw_gemm_body(W0, wp0, 256, 0, (b - 144) * 256 + t);
    else if (b < 184)  pw_gemm_body(W1, wp1, 256, 1, (b - 152) * 256 + t);
    else {
        int i = ((b - 184) * 256 + t) * 4;       // 49 blocks zero cnt[NN]
        if (i < NN) {
            cnt[i] = 0;
            if (i + 1 < NN) cnt[i + 1] = 0;
            if (i + 2 < NN) cnt[i + 2] = 0;
            if (i + 3 < NN) cnt[i + 3] = 0;
        }
    }
}

// ---------------------------------------------------------------------------
// Fusion (R18 2x18-phase staging) + INLINE layer-0 feat GEMM (R20).
// ---------------------------------------------------------------------------
__global__ __launch_bounds__(256) void fusion_mfma(
    const float* __restrict__ hc, const float* __restrict__ ht, const float* __restrict__ hr,
    const unsigned short* __restrict__ wpc, const unsigned short* __restrict__ wpt,
    const unsigned short* __restrict__ wpr, const unsigned short* __restrict__ wp0,
    const float* __restrict__ Wc, const float* __restrict__ Wt, const float* __restrict__ Wr,
    const float* __restrict__ fw, const float* __restrict__ fb,
    const float* __restrict__ al0, const float* __restrict__ ar0,
    unsigned short* __restrict__ featb, float* __restrict__ el, float* __restrict__ er)
{
    __shared__ __align__(16) float lds[18 * 512];    // 36,864B (stage/exchange/h0)
    float* ldsx = lds;
    unsigned short* ldsh = (unsigned short*)lds;     // 2KB h0 tile (aliased)
    const int w = threadIdx.x >> 6, l = threadIdx.x & 63;
    const int G = blockIdx.x, nb = G * 16;
    const int c_lo = l & 15;

    const int r0 = l >> 3;
    const int xs = ((l & 7) ^ (r0 & 7)) * 4;

    const int arow = l & 15;
    const int asl0 = ((l >> 4) * 2) ^ (arow & 7);
    const int asl1 = ((l >> 4) * 2 + 1) ^ (arow & 7);

    auto aread = [&](int slot) -> bf16x8 {
        const float* base = lds + slot * 512 + arow * 32;
        f32x4 a = *(const f32x4*)(base + asl0 * 4);
        f32x4 b = *(const f32x4*)(base + asl1 * 4);
        union { unsigned int wd[4]; bf16x8 v; } u;
        u.wd[0] = cvtpk(a[0], a[1]);
        u.wd[1] = cvtpk(a[2], a[3]);
        u.wd[2] = cvtpk(b[0], b[1]);
        u.wd[3] = cvtpk(b[2], b[3]);
        return u.v;
    };

    auto stage_half = [&](int half) {
        for (int cid = w; cid < 18; cid += 4) {
            int gcid = half * 18 + cid;
            const float* F; int K, kc;
            if (gcid < 4)       { F = hc; K = 129; kc = gcid; }
            else if (gcid < 20) { F = ht; K = 513; kc = gcid - 4; }
            else                { F = hr; K = 513; kc = gcid - 20; }
#pragma unroll
            for (int i = 0; i < 2; ++i) {
                const float* g = F + (size_t)(nb + i * 8 + r0) * K + kc * 32 + xs;
                gld_lds16(g, lds + cid * 512 + i * 256);
            }
        }
    };

    f32x4 prod[4], accT[4], acc[4];

    // ---- half 0: hc g0-3, ht kc0-13 ----
    stage_half(0);
    __syncthreads();

#pragma unroll
    for (int ct = 0; ct < 4; ++ct) {
        float wi = Wc[((size_t)w * 129 + 128) * 64 + ct * 16 + c_lo];
        prod[ct] = f32x4{wi, wi, wi, wi};
    }
#pragma unroll
    for (int kc = 0; kc < 4; ++kc) {
        bf16x8 af = aread(kc);
        const unsigned short* wk = wpc + (size_t)kc * 8192 + w * 512 + l * 8;
#pragma unroll
        for (int ct = 0; ct < 4; ++ct) {
            bf16x8 bf = *(const bf16x8*)(wk + ct * 2048);
            prod[ct] = __builtin_amdgcn_mfma_f32_16x16x32_bf16(af, bf, prod[ct], 0, 0, 0);
        }
    }
#pragma unroll
    for (int ct = 0; ct < 4; ++ct) {
        float wi = Wt[((size_t)w * 513 + 512) * 64 + ct * 16 + c_lo];
        accT[ct] = f32x4{wi, wi, wi, wi};
    }
#pragma unroll
    for (int kc = 0; kc < 14; ++kc) {
        bf16x8 af = aread(4 + kc);
        const unsigned short* wk = wpt + (size_t)kc * 8192 + w * 512 + l * 8;
#pragma unroll
        for (int ct = 0; ct < 4; ++ct) {
            bf16x8 bf = *(const bf16x8*)(wk + ct * 2048);
            accT[ct] = __builtin_amdgcn_mfma_f32_16x16x32_bf16(af, bf, accT[ct], 0, 0, 0);
        }
    }

    // ---- half 1: ht kc14-15 (slots 0-1), hr kc0-15 (slots 2-17) ----
    __syncthreads();
    stage_half(1);
    __syncthreads();

#pragma unroll
    for (int kc = 14; kc < 16; ++kc) {
        bf16x8 af = aread(kc - 14);
        const unsigned short* wk = wpt + (size_t)kc * 8192 + w * 512 + l * 8;
#pragma unroll
        for (int ct = 0; ct < 4; ++ct) {
            bf16x8 bf = *(const bf16x8*)(wk + ct * 2048);
            accT[ct] = __builtin_amdgcn_mfma_f32_16x16x32_bf16(af, bf, accT[ct], 0, 0, 0);
        }
    }
#pragma unroll
    for (int ct = 0; ct < 4; ++ct) {
        prod[ct] *= accT[ct];
        float wi = Wr[((size_t)w * 513 + 512) * 64 + ct * 16 + c_lo];
        acc[ct] = f32x4{wi, wi, wi, wi};
    }
#pragma unroll
    for (int kc = 0; kc < 16; ++kc) {
        bf16x8 af = aread(2 + kc);
        const unsigned short* wk = wpr + (size_t)kc * 8192 + w * 512 + l * 8;
#pragma unroll
        for (int ct = 0; ct < 4; ++ct) {
            bf16x8 bf = *(const bf16x8*)(wk + ct * 2048);
            acc[ct] = __builtin_amdgcn_mfma_f32_16x16x32_bf16(af, bf, acc[ct], 0, 0, 0);
        }
    }
    const float fww = fw[w];
#pragma unroll
    for (int ct = 0; ct < 4; ++ct) prod[ct] = prod[ct] * acc[ct] * fww;

    // ---- rank exchange ----
    __syncthreads();
#pragma unroll
    for (int ct = 0; ct < 4; ++ct)
        *(f32x4*)&ldsx[((w * 4 + ct) * 64 + l) * 4] = prod[ct];
    __syncthreads();

    f32x4 s = *(const f32x4*)&ldsx[((0 * 4 + w) * 64 + l) * 4];
#pragma unroll
    for (int r = 1; r < 4; ++r)
        s += *(const f32x4*)&ldsx[((r * 4 + w) * 64 + l) * 4];

    // ---- ELU + write h0 tile (bf16, slot-XOR swizzled) ----
    const float fbc = fb[w * 16 + c_lo];
    __syncthreads();
#pragma unroll
    for (int q = 0; q < 4; ++q) {
        int row = (l >> 4) * 4 + q;
        int ccol = w * 16 + c_lo;
        float v = s[q] + fbc;
        v = v > 0.f ? v : expm1f(v);
        ldsh[row * 64 + (((ccol >> 3) ^ (row & 7)) << 3) + (ccol & 7)] = f2b(v);
    }
    __syncthreads();

    // ---- inline layer-0 feat GEMM (K=64) ----
    f32x4 a4[4];
#pragma unroll
    for (int i = 0; i < 4; ++i) a4[i] = f32x4{0.f, 0.f, 0.f, 0.f};
#pragma unroll
    for (int kc = 0; kc < 2; ++kc) {
        int sl = (kc * 4 + (l >> 4)) ^ (arow & 7);
        bf16x8 af = *(const bf16x8*)(ldsh + arow * 64 + sl * 8);
        const unsigned short* wk = wp0 + ((size_t)kc * 16 + w * 4) * 512 + l * 8;
#pragma unroll
        for (int i = 0; i < 4; ++i) {
            bf16x8 bf = *(const bf16x8*)(wk + i * 512);
            a4[i] = __builtin_amdgcn_mfma_f32_16x16x32_bf16(af, bf, a4[i], 0, 0, 0);
        }
    }

    // feat store (head-minor) + fused el/er for head h = w
#pragma unroll
    for (int i = 0; i < 4; ++i) {
        int c = (w * 4 + i) * 16 + c_lo;
        int dm = (c & 63) * 4 + (c >> 6);
#pragma unroll
        for (int q = 0; q < 4; ++q) {
            int n = nb + (l >> 4) * 4 + q;
            featb[(size_t)n * 256 + dm] = f2b(a4[i][q]);
        }
    }
    float pel[4] = {0.f, 0.f, 0.f, 0.f};
    float per_[4] = {0.f, 0.f, 0.f, 0.f};
#pragma unroll
    for (int i = 0; i < 4; ++i) {
        int d = i * 16 + c_lo;
        float av = al0[w * 64 + d];
        float rv = ar0[w * 64 + d];
#pragma unroll
        for (int q = 0; q < 4; ++q) {
            pel[q] += a4[i][q] * av;
            per_[q] += a4[i][q] * rv;
        }
    }
#pragma unroll
    for (int off = 1; off <= 8; off <<= 1) {
#pragma unroll
        for (int q = 0; q < 4; ++q) {
            pel[q] += __shfl_xor(pel[q], off);
            per_[q] += __shfl_xor(per_[q], off);
        }
    }
    int qsel = l & 15;
    if (qsel < 4) {
        float ev = qsel == 0 ? pel[0] : qsel == 1 ? pel[1] : qsel == 2 ? pel[2] : pel[3];
        float rv = qsel == 0 ? per_[0] : qsel == 1 ? per_[1] : qsel == 2 ? per_[2] : per_[3];
        int n = nb + (l >> 4) * 4 + qsel;
        el[(size_t)n * 4 + w] = ev;
        er[(size_t)n * 4 + w] = rv;
    }
}

// ---------------------------------------------------------------------------
// feat GEMM with FUSED el/er epilogue (layer 1 only). HEAD-MINOR output.
// ---------------------------------------------------------------------------
template<int K>
__global__ __launch_bounds__(256) void gemm_reg(
    const unsigned short* __restrict__ Ab, const unsigned short* __restrict__ wp,
    const float* __restrict__ al, const float* __restrict__ ar,
    unsigned short* __restrict__ featb,
    float* __restrict__ el, float* __restrict__ er)
{
    constexpr int NKC = K / 32;
    const int w = threadIdx.x >> 6, l = threadIdx.x & 63;
    const int nb = blockIdx.x * 16;

    f32x4 acc[4];
#pragma unroll
    for (int i = 0; i < 4; ++i) acc[i] = f32x4{0.f, 0.f, 0.f, 0.f};

    const unsigned short* abase = Ab + (size_t)(nb + (l & 15)) * K + (l >> 4) * 8;
    bf16x8 afs[NKC];
#pragma unroll
    for (int kc = 0; kc < NKC; ++kc)
        afs[kc] = *(const bf16x8*)(abase + kc * 32);

    bf16x8 bcur[4];
    {
        const unsigned short* wk = wp + (size_t)(0 * 16 + w * 4) * 512 + l * 8;
#pragma unroll
        for (int i = 0; i < 4; ++i) bcur[i] = *(const bf16x8*)(wk + i * 512);
    }
#pragma unroll
    for (int kc = 0; kc < NKC; ++kc) {
        bf16x8 bnxt[4];
        if (kc + 1 < NKC) {
            const unsigned short* wk = wp + ((size_t)(kc + 1) * 16 + w * 4) * 512 + l * 8;
#pragma unroll
            for (int i = 0; i < 4; ++i) bnxt[i] = *(const bf16x8*)(wk + i * 512);
        }
#pragma unroll
        for (int i = 0; i < 4; ++i)
            acc[i] = __builtin_amdgcn_mfma_f32_16x16x32_bf16(afs[kc], bcur[i], acc[i], 0, 0, 0);
        if (kc + 1 < NKC) {
#pragma unroll
            for (int i = 0; i < 4; ++i) bcur[i] = bnxt[i];
        }
    }

#pragma unroll
    for (int i = 0; i < 4; ++i) {
        int c = (w * 4 + i) * 16 + (l & 15);
        int dm = (c & 63) * 4 + (c >> 6);
#pragma unroll
        for (int q = 0; q < 4; ++q) {
            int n = nb + (l >> 4) * 4 + q;
            featb[(size_t)n * 256 + dm] = f2b(acc[i][q]);
        }
    }

    float pel[4] = {0.f, 0.f, 0.f, 0.f};
    float per_[4] = {0.f, 0.f, 0.f, 0.f};
#pragma unroll
    for (int i = 0; i < 4; ++i) {
        int d = i * 16 + (l & 15);
        float av = al[w * 64 + d];
        float rv = ar[w * 64 + d];
#pragma unroll
        for (int q = 0; q < 4; ++q) {
            pel[q] += acc[i][q] * av;
            per_[q] += acc[i][q] * rv;
        }
    }
#pragma unroll
    for (int off = 1; off <= 8; off <<= 1) {
#pragma unroll
        for (int q = 0; q < 4; ++q) {
            pel[q] += __shfl_xor(pel[q], off);
            per_[q] += __shfl_xor(per_[q], off);
        }
    }
    int qsel = l & 15;
    if (qsel < 4) {
        float ev = qsel == 0 ? pel[0] : qsel == 1 ? pel[1] : qsel == 2 ? pel[2] : pel[3];
        float rv = qsel == 0 ? per_[0] : qsel == 1 ? per_[1] : qsel == 2 ? per_[2] : per_[3];
        int n = nb + (l >> 4) * 4 + qsel;
        el[(size_t)n * 4 + w] = ev;
        er[(size_t)n * 4 + w] = rv;
    }
}

// ---------------------------------------------------------------------------
// CSR build (cnt pre-zeroed by pack_all_w; scan re-zeroes for scatter)
// ---------------------------------------------------------------------------
__global__ void hist_kernel(const int* __restrict__ dst, int* __restrict__ cnt)
{
    int e = blockIdx.x * blockDim.x + threadIdx.x;
    if (e < EE) atomicAdd(&cnt[dst[e]], 1);
}

__global__ __launch_bounds__(1024) void scan_kernel(int* __restrict__ cnt, int* __restrict__ offs)
{
    __shared__ int tmp[1024];
    const int t = threadIdx.x;
    const int C = (NN + 1023) / 1024;
    int lo = t * C, hi = min(lo + C, NN);
    int s = 0;
    for (int i = lo; i < hi; ++i) s += cnt[i];
    tmp[t] = s;
    __syncthreads();
    for (int off = 1; off < 1024; off <<= 1) {
        int v = (t >= off) ? tmp[t - off] : 0;
        __syncthreads();
        tmp[t] += v;
        __syncthreads();
    }
    int run = (t == 0) ? 0 : tmp[t - 1];
    for (int i = lo; i < hi; ++i) { offs[i] = run; run += cnt[i]; cnt[i] = 0; }
    if (t == 1023) offs[NN] = tmp[1023];
}

__global__ void scatter_kernel(const int* __restrict__ dst, const int* __restrict__ offs,
                               int* __restrict__ cur, int* __restrict__ esort)
{
    int e = blockIdx.x * blockDim.x + threadIdx.x;
    if (e < EE) {
        int d = dst[e];
        int p = offs[d] + atomicAdd(&cur[d], 1);
        esort[p] = e;
    }
}

// ---------------------------------------------------------------------------
// gat_agg, register-cached softmax; aggregation unrolled x2 (dual gathers +
// dual accumulator chains -> 2x gather MLP, half FMA chain depth).
// ---------------------------------------------------------------------------
template <int RESID, int WATT, int WB16, int WF32>
__global__ __launch_bounds__(256) void gat_agg(
    const int* __restrict__ esort, const int* __restrict__ src, const int* __restrict__ offs,
    const unsigned short* __restrict__ featb,
    const float* __restrict__ el, const float* __restrict__ er,
    const unsigned short* __restrict__ residb, const float* __restrict__ bias,
    float* __restrict__ out, unsigned short* __restrict__ outb,
    float4* __restrict__ att)
{
    int n = (int)((blockIdx.x * (size_t)blockDim.x + threadIdx.x) >> 6);
    int lane = threadIdx.x & 63;
    if (n >= NN) return;
    const int s0 = offs[n], s1 = offs[n + 1], deg = s1 - s0;
    const float4 r4 = *(const float4*)(er + (size_t)n * 4);

    float a0 = 0.f, a1 = 0.f, a2 = 0.f, a3 = 0.f;
    float i0, i1, i2, i3;

    if (deg <= 64) {
        int p = s0 + lane;
        bool valid = p < s1;
        int e = valid ? esort[p] : 0;
        int sv = valid ? src[e] : 0;
        float v0 = -1e30f, v1 = -1e30f, v2 = -1e30f, v3 = -1e30f;
        if (valid) {
            float4 l4 = *(const float4*)(el + (size_t)sv * 4);
            v0 = lrelu(l4.x + r4.x); v1 = lrelu(l4.y + r4.y);
            v2 = lrelu(l4.z + r4.z); v3 = lrelu(l4.w + r4.w);
        }
        float m0 = v0, m1 = v1, m2 = v2, m3 = v3;
#pragma unroll
        for (int off = 32; off; off >>= 1) {
            m0 = fmaxf(m0, __shfl_xor(m0, off));
            m1 = fmaxf(m1, __shfl_xor(m1, off));
            m2 = fmaxf(m2, __shfl_xor(m2, off));
            m3 = fmaxf(m3, __shfl_xor(m3, off));
        }
        float e0 = valid ? expf(v0 - m0) : 0.f;
        float e1 = valid ? expf(v1 - m1) : 0.f;
        float e2 = valid ? expf(v2 - m2) : 0.f;
        float e3 = valid ? expf(v3 - m3) : 0.f;
        float z0 = e0, z1 = e1, z2 = e2, z3 = e3;
#pragma unroll
        for (int off = 32; off; off >>= 1) {
            z0 += __shfl_xor(z0, off);
            z1 += __shfl_xor(z1, off);
            z2 += __shfl_xor(z2, off);
            z3 += __shfl_xor(z3, off);
        }
        float j0 = z0 > 0.f ? 1.f / z0 : 0.f;
        float j1 = z1 > 0.f ? 1.f / z1 : 0.f;
        float j2 = z2 > 0.f ? 1.f / z2 : 0.f;
        float j3 = z3 > 0.f ? 1.f / z3 : 0.f;
        e0 *= j0; e1 *= j1; e2 *= j2; e3 *= j3;
        if (WATT && valid)
            att[e] = make_float4(e0, e1, e2, e3);
        float c0 = 0.f, c1 = 0.f, c2 = 0.f, c3 = 0.f;
        int jj = 0;
        for (; jj + 1 < deg; jj += 2) {
            float wA0 = __shfl(e0, jj),     wA1 = __shfl(e1, jj);
            float wA2 = __shfl(e2, jj),     wA3 = __shfl(e3, jj);
            float wB0 = __shfl(e0, jj + 1), wB1 = __shfl(e1, jj + 1);
            float wB2 = __shfl(e2, jj + 1), wB3 = __shfl(e3, jj + 1);
            int sA = __shfl(sv, jj), sB = __shfl(sv, jj + 1);
            ushort4 fA = *(const ushort4*)(featb + (size_t)sA * 256 + lane * 4);
            ushort4 fB = *(const ushort4*)(featb + (size_t)sB * 256 + lane * 4);
            a0 += wA0 * b2f(fA.x);  c0 += wB0 * b2f(fB.x);
            a1 += wA1 * b2f(fA.y);  c1 += wB1 * b2f(fB.y);
            a2 += wA2 * b2f(fA.z);  c2 += wB2 * b2f(fB.z);
            a3 += wA3 * b2f(fA.w);  c3 += wB3 * b2f(fB.w);
        }
        if (jj < deg) {
            float w0 = __shfl(e0, jj), w1 = __shfl(e1, jj);
            float w2 = __shfl(e2, jj), w3 = __shfl(e3, jj);
            int s = __shfl(sv, jj);
            ushort4 f = *(const ushort4*)(featb + (size_t)s * 256 + lane * 4);
            a0 += w0 * b2f(f.x);
            a1 += w1 * b2f(f.y);
            a2 += w2 * b2f(f.z);
            a3 += w3 * b2f(f.w);
        }
        a0 += c0; a1 += c1; a2 += c2; a3 += c3;
        i0 = i1 = i2 = i3 = 1.f;
    } else {
        float m0 = -1e30f, m1 = -1e30f, m2 = -1e30f, m3 = -1e30f;
        for (int p = s0 + lane; p < s1; p += 64) {
            int s = src[esort[p]];
            float4 l4 = *(const float4*)(el + (size_t)s * 4);
            m0 = fmaxf(m0, lrelu(l4.x + r4.x));
            m1 = fmaxf(m1, lrelu(l4.y + r4.y));
            m2 = fmaxf(m2, lrelu(l4.z + r4.z));
            m3 = fmaxf(m3, lrelu(l4.w + r4.w));
        }
#pragma unroll
        for (int off = 32; off; off >>= 1) {
            m0 = fmaxf(m0, __shfl_xor(m0, off));
            m1 = fmaxf(m1, __shfl_xor(m1, off));
            m2 = fmaxf(m2, __shfl_xor(m2, off));
            m3 = fmaxf(m3, __shfl_xor(m3, off));
        }
        float z0 = 0.f, z1 = 0.f, z2 = 0.f, z3 = 0.f;
        for (int p = s0 + lane; p < s1; p += 64) {
            int s = src[esort[p]];
            float4 l4 = *(const float4*)(el + (size_t)s * 4);
            z0 += expf(lrelu(l4.x + r4.x) - m0);
            z1 += expf(lrelu(l4.y + r4.y) - m1);
            z2 += expf(lrelu(l4.z + r4.z) - m2);
            z3 += expf(lrelu(l4.w + r4.w) - m3);
        }
#pragma unroll
        for (int off = 32; off; off >>= 1) {
            z0 += __shfl_xor(z0, off);
            z1 += __shfl_xor(z1, off);
            z2 += __shfl_xor(z2, off);
            z3 += __shfl_xor(z3, off);
        }
        i0 = z0 > 0.f ? 1.f / z0 : 0.f;
        i1 = z1 > 0.f ? 1.f / z1 : 0.f;
        i2 = z2 > 0.f ? 1.f / z2 : 0.f;
        i3 = z3 > 0.f ? 1.f / z3 : 0.f;
        for (int p = s0; p < s1; ++p) {
            int e = esort[p];
            int s = src[e];
            float4 l4 = *(const float4*)(el + (size_t)s * 4);
            float w0 = expf(lrelu(l4.x + r4.x) - m0);
            float w1 = expf(lrelu(l4.y + r4.y) - m1);
            float w2 = expf(lrelu(l4.z + r4.z) - m2);
            float w3 = expf(lrelu(l4.w + r4.w) - m3);
            ushort4 f = *(const ushort4*)(featb + (size_t)s * 256 + lane * 4);
            a0 += w0 * b2f(f.x);
            a1 += w1 * b2f(f.y);
            a2 += w2 * b2f(f.z);
            a3 += w3 * b2f(f.w);
            if (WATT && lane == 0)
                att[e] = make_float4(w0 * i0, w1 * i1, w2 * i2, w3 * i3);
        }
    }

    float o0 = a0 * i0 + bias[lane];
    float o1 = a1 * i1 + bias[64 + lane];
    float o2 = a2 * i2 + bias[128 + lane];
    float o3 = a3 * i3 + bias[192 + lane];
    if (RESID) {
        ushort4 rp = *(const ushort4*)(residb + (size_t)n * 256 + lane * 4);
        o0 += b2f(rp.x); o1 += b2f(rp.y); o2 += b2f(rp.z); o3 += b2f(rp.w);
    }
    if (WF32) {
        float* op = out + (size_t)n * 256;
        op[lane] = o0;
        op[64 + lane] = o1;
        op[128 + lane] = o2;
        op[192 + lane] = o3;
    }
    if (WB16) {
        ushort4 ob;
        ob.x = f2b(o0); ob.y = f2b(o1); ob.z = f2b(o2); ob.w = f2b(o3);
        *(ushort4*)(outb + (size_t)n * 256 + lane * 4) = ob;
    }
}

// ---------------------------------------------------------------------------
extern "C" void kernel_launch(void* const* d_in, const int* in_sizes, int n_in,
                              void* d_out, int out_size, void* d_ws, size_t ws_size,
                              hipStream_t stream)
{
    const int*   src = (const int*)d_in[0];
    const int*   dst = (const int*)d_in[1];
    const float* hc  = (const float*)d_in[2];
    const float* ht  = (const float*)d_in[3];
    const float* hr  = (const float*)d_in[4];
    const float* Wc  = (const float*)d_in[5];
    const float* Wt  = (const float*)d_in[6];
    const float* Wr  = (const float*)d_in[7];
    const float* fw  = (const float*)d_in[8];
    const float* fb  = (const float*)d_in[9];
    const float* W0  = (const float*)d_in[10];
    const float* al0 = (const float*)d_in[11];
    const float* ar0 = (const float*)d_in[12];
    const float* b0  = (const float*)d_in[13];
    const float* W1  = (const float*)d_in[14];
    const float* al1 = (const float*)d_in[15];
    const float* ar1 = (const float*)d_in[16];
    const float* b1  = (const float*)d_in[17];

    // workspace layout (bytes); proven ws_size >= 63,553,792
    char* ws = (char*)d_ws;
    unsigned short* h1b   = (unsigned short*)(ws + 6400000);     // N*256 bf16 (head-minor)
    unsigned short* featb = (unsigned short*)(ws + 32000000);    // N*256 bf16 (head-minor)
    float* el    = (float*)(ws + 57600000);                      //    800,000
    float* er    = (float*)(ws + 58400000);                      //    800,000
    int*   cnt   = (int*)  (ws + 59200000);                      //    200,000
    int*   offs  = (int*)  (ws + 59400000);                      //    200,064 (padded)
    int*   esort = (int*)  (ws + 59600128);                      //  3,200,000
    unsigned short* wpc = (unsigned short*)(ws + 62800128);      //  4*16KB
    unsigned short* wpt = (unsigned short*)(ws + 62865664);      // 16*16KB
    unsigned short* wpr = (unsigned short*)(ws + 63127808);      // 16*16KB
    unsigned short* wp0 = (unsigned short*)(ws + 63389952);      //  2*16KB
    unsigned short* wp1 = (unsigned short*)(ws + 63422720);      //  8*16KB
    if (ws_size < 63553792ull) return;                           // end of layout

    float* outh = (float*)d_out;                       // N*256 final h
    float4* atto = (float4*)(outh + (size_t)NN * 256); // E*4 att region

    // weight packing + cnt zeroing (single dispatch; 184 pack + 49 zero blocks)
    pack_all_w<<<233, 256, 0, stream>>>(Wc, Wt, Wr, W0, W1,
                                        wpc, wpt, wpr, wp0, wp1, cnt);

    // trilinear fusion + inline layer-0 feat GEMM (featb/el/er out)
    fusion_mfma<<<NG, 256, 0, stream>>>(hc, ht, hr, wpc, wpt, wpr, wp0,
                                        Wc, Wt, Wr, fw, fb, al0, ar0,
                                        featb, el, er);

    // CSR by dst
    hist_kernel<<<(EE + 255) / 256, 256, 0, stream>>>(dst, cnt);
    scan_kernel<<<1, 1024, 0, stream>>>(cnt, offs);
    scatter_kernel<<<(EE + 255) / 256, 256, 0, stream>>>(dst, offs, cnt, esort);

    // GAT layer 0: softmax+agg in-register; bf16 h1b out
    gat_agg<0, 0, 1, 0><<<(NN * 64 + 255) / 256, 256, 0, stream>>>(
        esort, src, offs, featb, el, er, nullptr, b0, nullptr, h1b, nullptr);

    // GAT layer 1: feat + el/er fused; residual from bf16 h1b; f32 out + att
    gemm_reg<256><<<NG, 256, 0, stream>>>(h1b, wp1, al1, ar1, featb, el, er);
    gat_agg<1, 1, 0, 1><<<(NN * 64 + 255) / 256, 256, 0, stream>>>(
        esort, src, offs, featb, el, er, h1b, b1, outh, nullptr, atto);
}

// Round 22
// 503.775 us; speedup vs baseline: 1.0664x; 1.0158x over previous
//
#include <hip/hip_runtime.h>
#include <math.h>

#define NN 50000
#define EE 800000
#define NEG 0.2f
#define NG (NN / 16)   // 3125 node groups

using f32x4  = __attribute__((ext_vector_type(4))) float;
using bf16x8 = __attribute__((ext_vector_type(8))) short;

__device__ __forceinline__ float lrelu(float x){ return x > 0.f ? x : NEG*x; }

__device__ __forceinline__ unsigned short f2b(float f){
    unsigned int u = __float_as_uint(f);
    return (unsigned short)((u + 0x7FFFu + ((u >> 16) & 1u)) >> 16);  // RNE
}
__device__ __forceinline__ float b2f(unsigned short h){
    return __uint_as_float(((unsigned int)h) << 16);
}
__device__ __forceinline__ void gld_lds16(const void* g, void* l){
    __builtin_amdgcn_global_load_lds(
        (const __attribute__((address_space(1))) unsigned int*)g,
        (__attribute__((address_space(3))) unsigned int*)l, 16, 0, 0);
}
__device__ __forceinline__ unsigned int cvtpk(float lo, float hi){
    unsigned int r;
    asm volatile("v_cvt_pk_bf16_f32 %0, %1, %2" : "=v"(r) : "v"(lo), "v"(hi));
    return r;
}

// ---------------------------------------------------------------------------
// Combined weight packer + cnt zeroing (1 dispatch). Fragment-order bf16.
// ---------------------------------------------------------------------------
__device__ __forceinline__ void pw_fusion_body(
    const float* __restrict__ W, unsigned short* __restrict__ out, int K, int u)
{
    int l = u & 63, chunk = (u >> 6) & 15, kc = u >> 10;
    int ct = chunk >> 2, r = chunk & 3;
    int c = ct * 16 + (l & 15);
    int kb = kc * 32 + (l >> 4) * 8;
    bf16x8 v;
#pragma unroll
    for (int j = 0; j < 8; ++j)
        v[j] = (short)f2b(W[((size_t)r * K + kb + j) * 64 + c]);
    *(bf16x8*)(out + (size_t)u * 8) = v;
}

__device__ __forceinline__ void pw_gemm_body(
    const float* __restrict__ W, unsigned short* __restrict__ out,
    int C, int PERM, int u)
{
    int NCH = C / 16;
    int l = u & 63, ch = (u >> 6) % NCH, kc = u / (64 * NCH);
    int c = ch * 16 + (l & 15);
    int kb = kc * 32 + (l >> 4) * 8;
    bf16x8 v;
#pragma unroll
    for (int j = 0; j < 8; ++j) {
        int k = kb + j;
        int ko = PERM ? ((k & 3) * 64 + (k >> 2)) : k;
        v[j] = (short)f2b(W[(size_t)ko * C + c]);
    }
    *(bf16x8*)(out + (size_t)u * 8) = v;
}

__global__ __launch_bounds__(256) void pack_all_w(
    const float* __restrict__ Wc, const float* __restrict__ Wt, const float* __restrict__ Wr,
    const float* __restrict__ W0, const float* __restrict__ W1,
    unsigned short* __restrict__ wpc, unsigned short* __restrict__ wpt,
    unsigned short* __restrict__ wpr, unsigned short* __restrict__ wp0,
    unsigned short* __restrict__ wp1, int* __restrict__ cnt)
{
    int b = blockIdx.x, t = threadIdx.x;
    if (b < 16)        pw_fusion_body(Wc, wpc, 129, b * 256 + t);
    else if (b < 80)   pw_fusion_body(Wt, wpt, 513, (b - 16) * 256 + t);
    else if (b < 144)  pw_fusion_body(Wr, wpr, 513, (b - 80) * 256 + t);
    else if (b < 152)  pw_gemm_body(W0, wp0, 256, 0, (b - 144) * 256 + t);
    else if (b < 184)  pw_gemm_body(W1, wp1, 256, 1, (b - 152) * 256 + t);
    else {
        int i = ((b - 184) * 256 + t) * 4;       // 49 blocks zero cnt[NN]
        if (i < NN) {
            cnt[i] = 0;
            if (i + 1 < NN) cnt[i + 1] = 0;
            if (i + 2 < NN) cnt[i + 2] = 0;
            if (i + 3 < NN) cnt[i + 3] = 0;
        }
    }
}

// ---------------------------------------------------------------------------
// Fusion (R18 2x18-phase staging) + INLINE layer-0 feat GEMM (R20).
// ---------------------------------------------------------------------------
__global__ __launch_bounds__(256) void fusion_mfma(
    const float* __restrict__ hc, const float* __restrict__ ht, const float* __restrict__ hr,
    const unsigned short* __restrict__ wpc, const unsigned short* __restrict__ wpt,
    const unsigned short* __restrict__ wpr, const unsigned short* __restrict__ wp0,
    const float* __restrict__ Wc, const float* __restrict__ Wt, const float* __restrict__ Wr,
    const float* __restrict__ fw, const float* __restrict__ fb,
    const float* __restrict__ al0, const float* __restrict__ ar0,
    unsigned short* __restrict__ featb, float* __restrict__ el, float* __restrict__ er)
{
    __shared__ __align__(16) float lds[18 * 512];    // 36,864B (stage/exchange/h0)
    float* ldsx = lds;
    unsigned short* ldsh = (unsigned short*)lds;     // 2KB h0 tile (aliased)
    const int w = threadIdx.x >> 6, l = threadIdx.x & 63;
    const int G = blockIdx.x, nb = G * 16;
    const int c_lo = l & 15;

    const int r0 = l >> 3;
    const int xs = ((l & 7) ^ (r0 & 7)) * 4;

    const int arow = l & 15;
    const int asl0 = ((l >> 4) * 2) ^ (arow & 7);
    const int asl1 = ((l >> 4) * 2 + 1) ^ (arow & 7);

    auto aread = [&](int slot) -> bf16x8 {
        const float* base = lds + slot * 512 + arow * 32;
        f32x4 a = *(const f32x4*)(base + asl0 * 4);
        f32x4 b = *(const f32x4*)(base + asl1 * 4);
        union { unsigned int wd[4]; bf16x8 v; } u;
        u.wd[0] = cvtpk(a[0], a[1]);
        u.wd[1] = cvtpk(a[2], a[3]);
        u.wd[2] = cvtpk(b[0], b[1]);
        u.wd[3] = cvtpk(b[2], b[3]);
        return u.v;
    };

    auto stage_half = [&](int half) {
        for (int cid = w; cid < 18; cid += 4) {
            int gcid = half * 18 + cid;
            const float* F; int K, kc;
            if (gcid < 4)       { F = hc; K = 129; kc = gcid; }
            else if (gcid < 20) { F = ht; K = 513; kc = gcid - 4; }
            else                { F = hr; K = 513; kc = gcid - 20; }
#pragma unroll
            for (int i = 0; i < 2; ++i) {
                const float* g = F + (size_t)(nb + i * 8 + r0) * K + kc * 32 + xs;
                gld_lds16(g, lds + cid * 512 + i * 256);
            }
        }
    };

    f32x4 prod[4], accT[4], acc[4];

    // ---- half 0: hc g0-3, ht kc0-13 ----
    stage_half(0);
    __syncthreads();

#pragma unroll
    for (int ct = 0; ct < 4; ++ct) {
        float wi = Wc[((size_t)w * 129 + 128) * 64 + ct * 16 + c_lo];
        prod[ct] = f32x4{wi, wi, wi, wi};
    }
#pragma unroll
    for (int kc = 0; kc < 4; ++kc) {
        bf16x8 af = aread(kc);
        const unsigned short* wk = wpc + (size_t)kc * 8192 + w * 512 + l * 8;
#pragma unroll
        for (int ct = 0; ct < 4; ++ct) {
            bf16x8 bf = *(const bf16x8*)(wk + ct * 2048);
            prod[ct] = __builtin_amdgcn_mfma_f32_16x16x32_bf16(af, bf, prod[ct], 0, 0, 0);
        }
    }
#pragma unroll
    for (int ct = 0; ct < 4; ++ct) {
        float wi = Wt[((size_t)w * 513 + 512) * 64 + ct * 16 + c_lo];
        accT[ct] = f32x4{wi, wi, wi, wi};
    }
#pragma unroll
    for (int kc = 0; kc < 14; ++kc) {
        bf16x8 af = aread(4 + kc);
        const unsigned short* wk = wpt + (size_t)kc * 8192 + w * 512 + l * 8;
#pragma unroll
        for (int ct = 0; ct < 4; ++ct) {
            bf16x8 bf = *(const bf16x8*)(wk + ct * 2048);
            accT[ct] = __builtin_amdgcn_mfma_f32_16x16x32_bf16(af, bf, accT[ct], 0, 0, 0);
        }
    }

    // ---- half 1: ht kc14-15 (slots 0-1), hr kc0-15 (slots 2-17) ----
    __syncthreads();
    stage_half(1);
    __syncthreads();

#pragma unroll
    for (int kc = 14; kc < 16; ++kc) {
        bf16x8 af = aread(kc - 14);
        const unsigned short* wk = wpt + (size_t)kc * 8192 + w * 512 + l * 8;
#pragma unroll
        for (int ct = 0; ct < 4; ++ct) {
            bf16x8 bf = *(const bf16x8*)(wk + ct * 2048);
            accT[ct] = __builtin_amdgcn_mfma_f32_16x16x32_bf16(af, bf, accT[ct], 0, 0, 0);
        }
    }
#pragma unroll
    for (int ct = 0; ct < 4; ++ct) {
        prod[ct] *= accT[ct];
        float wi = Wr[((size_t)w * 513 + 512) * 64 + ct * 16 + c_lo];
        acc[ct] = f32x4{wi, wi, wi, wi};
    }
#pragma unroll
    for (int kc = 0; kc < 16; ++kc) {
        bf16x8 af = aread(2 + kc);
        const unsigned short* wk = wpr + (size_t)kc * 8192 + w * 512 + l * 8;
#pragma unroll
        for (int ct = 0; ct < 4; ++ct) {
            bf16x8 bf = *(const bf16x8*)(wk + ct * 2048);
            acc[ct] = __builtin_amdgcn_mfma_f32_16x16x32_bf16(af, bf, acc[ct], 0, 0, 0);
        }
    }
    const float fww = fw[w];
#pragma unroll
    for (int ct = 0; ct < 4; ++ct) prod[ct] = prod[ct] * acc[ct] * fww;

    // ---- rank exchange ----
    __syncthreads();
#pragma unroll
    for (int ct = 0; ct < 4; ++ct)
        *(f32x4*)&ldsx[((w * 4 + ct) * 64 + l) * 4] = prod[ct];
    __syncthreads();

    f32x4 s = *(const f32x4*)&ldsx[((0 * 4 + w) * 64 + l) * 4];
#pragma unroll
    for (int r = 1; r < 4; ++r)
        s += *(const f32x4*)&ldsx[((r * 4 + w) * 64 + l) * 4];

    // ---- ELU + write h0 tile (bf16, slot-XOR swizzled) ----
    const float fbc = fb[w * 16 + c_lo];
    __syncthreads();
#pragma unroll
    for (int q = 0; q < 4; ++q) {
        int row = (l >> 4) * 4 + q;
        int ccol = w * 16 + c_lo;
        float v = s[q] + fbc;
        v = v > 0.f ? v : expm1f(v);
        ldsh[row * 64 + (((ccol >> 3) ^ (row & 7)) << 3) + (ccol & 7)] = f2b(v);
    }
    __syncthreads();

    // ---- inline layer-0 feat GEMM (K=64) ----
    f32x4 a4[4];
#pragma unroll
    for (int i = 0; i < 4; ++i) a4[i] = f32x4{0.f, 0.f, 0.f, 0.f};
#pragma unroll
    for (int kc = 0; kc < 2; ++kc) {
        int sl = (kc * 4 + (l >> 4)) ^ (arow & 7);
        bf16x8 af = *(const bf16x8*)(ldsh + arow * 64 + sl * 8);
        const unsigned short* wk = wp0 + ((size_t)kc * 16 + w * 4) * 512 + l * 8;
#pragma unroll
        for (int i = 0; i < 4; ++i) {
            bf16x8 bf = *(const bf16x8*)(wk + i * 512);
            a4[i] = __builtin_amdgcn_mfma_f32_16x16x32_bf16(af, bf, a4[i], 0, 0, 0);
        }
    }

    // feat store (head-minor) + fused el/er for head h = w
#pragma unroll
    for (int i = 0; i < 4; ++i) {
        int c = (w * 4 + i) * 16 + c_lo;
        int dm = (c & 63) * 4 + (c >> 6);
#pragma unroll
        for (int q = 0; q < 4; ++q) {
            int n = nb + (l >> 4) * 4 + q;
            featb[(size_t)n * 256 + dm] = f2b(a4[i][q]);
        }
    }
    float pel[4] = {0.f, 0.f, 0.f, 0.f};
    float per_[4] = {0.f, 0.f, 0.f, 0.f};
#pragma unroll
    for (int i = 0; i < 4; ++i) {
        int d = i * 16 + c_lo;
        float av = al0[w * 64 + d];
        float rv = ar0[w * 64 + d];
#pragma unroll
        for (int q = 0; q < 4; ++q) {
            pel[q] += a4[i][q] * av;
            per_[q] += a4[i][q] * rv;
        }
    }
#pragma unroll
    for (int off = 1; off <= 8; off <<= 1) {
#pragma unroll
        for (int q = 0; q < 4; ++q) {
            pel[q] += __shfl_xor(pel[q], off);
            per_[q] += __shfl_xor(per_[q], off);
        }
    }
    int qsel = l & 15;
    if (qsel < 4) {
        float ev = qsel == 0 ? pel[0] : qsel == 1 ? pel[1] : qsel == 2 ? pel[2] : pel[3];
        float rv = qsel == 0 ? per_[0] : qsel == 1 ? per_[1] : qsel == 2 ? per_[2] : per_[3];
        int n = nb + (l >> 4) * 4 + qsel;
        el[(size_t)n * 4 + w] = ev;
        er[(size_t)n * 4 + w] = rv;
    }
}

// ---------------------------------------------------------------------------
// feat GEMM with FUSED el/er epilogue (layer 1 only). HEAD-MINOR output.
// ---------------------------------------------------------------------------
template<int K>
__global__ __launch_bounds__(256) void gemm_reg(
    const unsigned short* __restrict__ Ab, const unsigned short* __restrict__ wp,
    const float* __restrict__ al, const float* __restrict__ ar,
    unsigned short* __restrict__ featb,
    float* __restrict__ el, float* __restrict__ er)
{
    constexpr int NKC = K / 32;
    const int w = threadIdx.x >> 6, l = threadIdx.x & 63;
    const int nb = blockIdx.x * 16;

    f32x4 acc[4];
#pragma unroll
    for (int i = 0; i < 4; ++i) acc[i] = f32x4{0.f, 0.f, 0.f, 0.f};

    const unsigned short* abase = Ab + (size_t)(nb + (l & 15)) * K + (l >> 4) * 8;
    bf16x8 afs[NKC];
#pragma unroll
    for (int kc = 0; kc < NKC; ++kc)
        afs[kc] = *(const bf16x8*)(abase + kc * 32);

    bf16x8 bcur[4];
    {
        const unsigned short* wk = wp + (size_t)(0 * 16 + w * 4) * 512 + l * 8;
#pragma unroll
        for (int i = 0; i < 4; ++i) bcur[i] = *(const bf16x8*)(wk + i * 512);
    }
#pragma unroll
    for (int kc = 0; kc < NKC; ++kc) {
        bf16x8 bnxt[4];
        if (kc + 1 < NKC) {
            const unsigned short* wk = wp + ((size_t)(kc + 1) * 16 + w * 4) * 512 + l * 8;
#pragma unroll
            for (int i = 0; i < 4; ++i) bnxt[i] = *(const bf16x8*)(wk + i * 512);
        }
#pragma unroll
        for (int i = 0; i < 4; ++i)
            acc[i] = __builtin_amdgcn_mfma_f32_16x16x32_bf16(afs[kc], bcur[i], acc[i], 0, 0, 0);
        if (kc + 1 < NKC) {
#pragma unroll
            for (int i = 0; i < 4; ++i) bcur[i] = bnxt[i];
        }
    }

#pragma unroll
    for (int i = 0; i < 4; ++i) {
        int c = (w * 4 + i) * 16 + (l & 15);
        int dm = (c & 63) * 4 + (c >> 6);
#pragma unroll
        for (int q = 0; q < 4; ++q) {
            int n = nb + (l >> 4) * 4 + q;
            featb[(size_t)n * 256 + dm] = f2b(acc[i][q]);
        }
    }

    float pel[4] = {0.f, 0.f, 0.f, 0.f};
    float per_[4] = {0.f, 0.f, 0.f, 0.f};
#pragma unroll
    for (int i = 0; i < 4; ++i) {
        int d = i * 16 + (l & 15);
        float av = al[w * 64 + d];
        float rv = ar[w * 64 + d];
#pragma unroll
        for (int q = 0; q < 4; ++q) {
            pel[q] += acc[i][q] * av;
            per_[q] += acc[i][q] * rv;
        }
    }
#pragma unroll
    for (int off = 1; off <= 8; off <<= 1) {
#pragma unroll
        for (int q = 0; q < 4; ++q) {
            pel[q] += __shfl_xor(pel[q], off);
            per_[q] += __shfl_xor(per_[q], off);
        }
    }
    int qsel = l & 15;
    if (qsel < 4) {
        float ev = qsel == 0 ? pel[0] : qsel == 1 ? pel[1] : qsel == 2 ? pel[2] : pel[3];
        float rv = qsel == 0 ? per_[0] : qsel == 1 ? per_[1] : qsel == 2 ? per_[2] : per_[3];
        int n = nb + (l >> 4) * 4 + qsel;
        el[(size_t)n * 4 + w] = ev;
        er[(size_t)n * 4 + w] = rv;
    }
}

// ---------------------------------------------------------------------------
// CSR build (cnt pre-zeroed by pack_all_w; scan re-zeroes for scatter)
// ---------------------------------------------------------------------------
__global__ void hist_kernel(const int* __restrict__ dst, int* __restrict__ cnt)
{
    int e = blockIdx.x * blockDim.x + threadIdx.x;
    if (e < EE) atomicAdd(&cnt[dst[e]], 1);
}

__global__ __launch_bounds__(1024) void scan_kernel(int* __restrict__ cnt, int* __restrict__ offs)
{
    __shared__ int tmp[1024];
    const int t = threadIdx.x;
    const int C = (NN + 1023) / 1024;
    int lo = t * C, hi = min(lo + C, NN);
    int s = 0;
    for (int i = lo; i < hi; ++i) s += cnt[i];
    tmp[t] = s;
    __syncthreads();
    for (int off = 1; off < 1024; off <<= 1) {
        int v = (t >= off) ? tmp[t - off] : 0;
        __syncthreads();
        tmp[t] += v;
        __syncthreads();
    }
    int run = (t == 0) ? 0 : tmp[t - 1];
    for (int i = lo; i < hi; ++i) { offs[i] = run; run += cnt[i]; cnt[i] = 0; }
    if (t == 1023) offs[NN] = tmp[1023];
}

__global__ void scatter_kernel(const int* __restrict__ dst, const int* __restrict__ offs,
                               int* __restrict__ cur, int* __restrict__ esort)
{
    int e = blockIdx.x * blockDim.x + threadIdx.x;
    if (e < EE) {
        int d = dst[e];
        int p = offs[d] + atomicAdd(&cur[d], 1);
        esort[p] = e;
    }
}

// ---------------------------------------------------------------------------
// gat_agg, register-cached softmax; aggregation unrolled x4 (4 gathers in
// flight, dual accumulator chains).
// ---------------------------------------------------------------------------
template <int RESID, int WATT, int WB16, int WF32>
__global__ __launch_bounds__(256) void gat_agg(
    const int* __restrict__ esort, const int* __restrict__ src, const int* __restrict__ offs,
    const unsigned short* __restrict__ featb,
    const float* __restrict__ el, const float* __restrict__ er,
    const unsigned short* __restrict__ residb, const float* __restrict__ bias,
    float* __restrict__ out, unsigned short* __restrict__ outb,
    float4* __restrict__ att)
{
    int n = (int)((blockIdx.x * (size_t)blockDim.x + threadIdx.x) >> 6);
    int lane = threadIdx.x & 63;
    if (n >= NN) return;
    const int s0 = offs[n], s1 = offs[n + 1], deg = s1 - s0;
    const float4 r4 = *(const float4*)(er + (size_t)n * 4);

    float a0 = 0.f, a1 = 0.f, a2 = 0.f, a3 = 0.f;
    float i0, i1, i2, i3;

    if (deg <= 64) {
        int p = s0 + lane;
        bool valid = p < s1;
        int e = valid ? esort[p] : 0;
        int sv = valid ? src[e] : 0;
        float v0 = -1e30f, v1 = -1e30f, v2 = -1e30f, v3 = -1e30f;
        if (valid) {
            float4 l4 = *(const float4*)(el + (size_t)sv * 4);
            v0 = lrelu(l4.x + r4.x); v1 = lrelu(l4.y + r4.y);
            v2 = lrelu(l4.z + r4.z); v3 = lrelu(l4.w + r4.w);
        }
        float m0 = v0, m1 = v1, m2 = v2, m3 = v3;
#pragma unroll
        for (int off = 32; off; off >>= 1) {
            m0 = fmaxf(m0, __shfl_xor(m0, off));
            m1 = fmaxf(m1, __shfl_xor(m1, off));
            m2 = fmaxf(m2, __shfl_xor(m2, off));
            m3 = fmaxf(m3, __shfl_xor(m3, off));
        }
        float e0 = valid ? expf(v0 - m0) : 0.f;
        float e1 = valid ? expf(v1 - m1) : 0.f;
        float e2 = valid ? expf(v2 - m2) : 0.f;
        float e3 = valid ? expf(v3 - m3) : 0.f;
        float z0 = e0, z1 = e1, z2 = e2, z3 = e3;
#pragma unroll
        for (int off = 32; off; off >>= 1) {
            z0 += __shfl_xor(z0, off);
            z1 += __shfl_xor(z1, off);
            z2 += __shfl_xor(z2, off);
            z3 += __shfl_xor(z3, off);
        }
        float j0 = z0 > 0.f ? 1.f / z0 : 0.f;
        float j1 = z1 > 0.f ? 1.f / z1 : 0.f;
        float j2 = z2 > 0.f ? 1.f / z2 : 0.f;
        float j3 = z3 > 0.f ? 1.f / z3 : 0.f;
        e0 *= j0; e1 *= j1; e2 *= j2; e3 *= j3;
        if (WATT && valid)
            att[e] = make_float4(e0, e1, e2, e3);
        float c0 = 0.f, c1 = 0.f, c2 = 0.f, c3 = 0.f;
        int jj = 0;
        for (; jj + 3 < deg; jj += 4) {
            int sA = __shfl(sv, jj),     sB = __shfl(sv, jj + 1);
            int sC = __shfl(sv, jj + 2), sD = __shfl(sv, jj + 3);
            ushort4 fA = *(const ushort4*)(featb + (size_t)sA * 256 + lane * 4);
            ushort4 fB = *(const ushort4*)(featb + (size_t)sB * 256 + lane * 4);
            ushort4 fC = *(const ushort4*)(featb + (size_t)sC * 256 + lane * 4);
            ushort4 fD = *(const ushort4*)(featb + (size_t)sD * 256 + lane * 4);
            float wA0 = __shfl(e0, jj),     wA1 = __shfl(e1, jj);
            float wA2 = __shfl(e2, jj),     wA3 = __shfl(e3, jj);
            float wB0 = __shfl(e0, jj + 1), wB1 = __shfl(e1, jj + 1);
            float wB2 = __shfl(e2, jj + 1), wB3 = __shfl(e3, jj + 1);
            float wC0 = __shfl(e0, jj + 2), wC1 = __shfl(e1, jj + 2);
            float wC2 = __shfl(e2, jj + 2), wC3 = __shfl(e3, jj + 2);
            float wD0 = __shfl(e0, jj + 3), wD1 = __shfl(e1, jj + 3);
            float wD2 = __shfl(e2, jj + 3), wD3 = __shfl(e3, jj + 3);
            a0 += wA0 * b2f(fA.x);  c0 += wB0 * b2f(fB.x);
            a1 += wA1 * b2f(fA.y);  c1 += wB1 * b2f(fB.y);
            a2 += wA2 * b2f(fA.z);  c2 += wB2 * b2f(fB.z);
            a3 += wA3 * b2f(fA.w);  c3 += wB3 * b2f(fB.w);
            a0 += wC0 * b2f(fC.x);  c0 += wD0 * b2f(fD.x);
            a1 += wC1 * b2f(fC.y);  c1 += wD1 * b2f(fD.y);
            a2 += wC2 * b2f(fC.z);  c2 += wD2 * b2f(fD.z);
            a3 += wC3 * b2f(fC.w);  c3 += wD3 * b2f(fD.w);
        }
        for (; jj < deg; ++jj) {
            float w0 = __shfl(e0, jj), w1 = __shfl(e1, jj);
            float w2 = __shfl(e2, jj), w3 = __shfl(e3, jj);
            int s = __shfl(sv, jj);
            ushort4 f = *(const ushort4*)(featb + (size_t)s * 256 + lane * 4);
            a0 += w0 * b2f(f.x);
            a1 += w1 * b2f(f.y);
            a2 += w2 * b2f(f.z);
            a3 += w3 * b2f(f.w);
        }
        a0 += c0; a1 += c1; a2 += c2; a3 += c3;
        i0 = i1 = i2 = i3 = 1.f;
    } else {
        float m0 = -1e30f, m1 = -1e30f, m2 = -1e30f, m3 = -1e30f;
        for (int p = s0 + lane; p < s1; p += 64) {
            int s = src[esort[p]];
            float4 l4 = *(const float4*)(el + (size_t)s * 4);
            m0 = fmaxf(m0, lrelu(l4.x + r4.x));
            m1 = fmaxf(m1, lrelu(l4.y + r4.y));
            m2 = fmaxf(m2, lrelu(l4.z + r4.z));
            m3 = fmaxf(m3, lrelu(l4.w + r4.w));
        }
#pragma unroll
        for (int off = 32; off; off >>= 1) {
            m0 = fmaxf(m0, __shfl_xor(m0, off));
            m1 = fmaxf(m1, __shfl_xor(m1, off));
            m2 = fmaxf(m2, __shfl_xor(m2, off));
            m3 = fmaxf(m3, __shfl_xor(m3, off));
        }
        float z0 = 0.f, z1 = 0.f, z2 = 0.f, z3 = 0.f;
        for (int p = s0 + lane; p < s1; p += 64) {
            int s = src[esort[p]];
            float4 l4 = *(const float4*)(el + (size_t)s * 4);
            z0 += expf(lrelu(l4.x + r4.x) - m0);
            z1 += expf(lrelu(l4.y + r4.y) - m1);
            z2 += expf(lrelu(l4.z + r4.z) - m2);
            z3 += expf(lrelu(l4.w + r4.w) - m3);
        }
#pragma unroll
        for (int off = 32; off; off >>= 1) {
            z0 += __shfl_xor(z0, off);
            z1 += __shfl_xor(z1, off);
            z2 += __shfl_xor(z2, off);
            z3 += __shfl_xor(z3, off);
        }
        i0 = z0 > 0.f ? 1.f / z0 : 0.f;
        i1 = z1 > 0.f ? 1.f / z1 : 0.f;
        i2 = z2 > 0.f ? 1.f / z2 : 0.f;
        i3 = z3 > 0.f ? 1.f / z3 : 0.f;
        for (int p = s0; p < s1; ++p) {
            int e = esort[p];
            int s = src[e];
            float4 l4 = *(const float4*)(el + (size_t)s * 4);
            float w0 = expf(lrelu(l4.x + r4.x) - m0);
            float w1 = expf(lrelu(l4.y + r4.y) - m1);
            float w2 = expf(lrelu(l4.z + r4.z) - m2);
            float w3 = expf(lrelu(l4.w + r4.w) - m3);
            ushort4 f = *(const ushort4*)(featb + (size_t)s * 256 + lane * 4);
            a0 += w0 * b2f(f.x);
            a1 += w1 * b2f(f.y);
            a2 += w2 * b2f(f.z);
            a3 += w3 * b2f(f.w);
            if (WATT && lane == 0)
                att[e] = make_float4(w0 * i0, w1 * i1, w2 * i2, w3 * i3);
        }
    }

    float o0 = a0 * i0 + bias[lane];
    float o1 = a1 * i1 + bias[64 + lane];
    float o2 = a2 * i2 + bias[128 + lane];
    float o3 = a3 * i3 + bias[192 + lane];
    if (RESID) {
        ushort4 rp = *(const ushort4*)(residb + (size_t)n * 256 + lane * 4);
        o0 += b2f(rp.x); o1 += b2f(rp.y); o2 += b2f(rp.z); o3 += b2f(rp.w);
    }
    if (WF32) {
        float* op = out + (size_t)n * 256;
        op[lane] = o0;
        op[64 + lane] = o1;
        op[128 + lane] = o2;
        op[192 + lane] = o3;
    }
    if (WB16) {
        ushort4 ob;
        ob.x = f2b(o0); ob.y = f2b(o1); ob.z = f2b(o2); ob.w = f2b(o3);
        *(ushort4*)(outb + (size_t)n * 256 + lane * 4) = ob;
    }
}

// ---------------------------------------------------------------------------
extern "C" void kernel_launch(void* const* d_in, const int* in_sizes, int n_in,
                              void* d_out, int out_size, void* d_ws, size_t ws_size,
                              hipStream_t stream)
{
    const int*   src = (const int*)d_in[0];
    const int*   dst = (const int*)d_in[1];
    const float* hc  = (const float*)d_in[2];
    const float* ht  = (const float*)d_in[3];
    const float* hr  = (const float*)d_in[4];
    const float* Wc  = (const float*)d_in[5];
    const float* Wt  = (const float*)d_in[6];
    const float* Wr  = (const float*)d_in[7];
    const float* fw  = (const float*)d_in[8];
    const float* fb  = (const float*)d_in[9];
    const float* W0  = (const float*)d_in[10];
    const float* al0 = (const float*)d_in[11];
    const float* ar0 = (const float*)d_in[12];
    const float* b0  = (const float*)d_in[13];
    const float* W1  = (const float*)d_in[14];
    const float* al1 = (const float*)d_in[15];
    const float* ar1 = (const float*)d_in[16];
    const float* b1  = (const float*)d_in[17];

    // workspace layout (bytes); proven ws_size >= 63,553,792
    char* ws = (char*)d_ws;
    unsigned short* h1b   = (unsigned short*)(ws + 6400000);     // N*256 bf16 (head-minor)
    unsigned short* featb = (unsigned short*)(ws + 32000000);    // N*256 bf16 (head-minor)
    float* el    = (float*)(ws + 57600000);                      //    800,000
    float* er    = (float*)(ws + 58400000);                      //    800,000
    int*   cnt   = (int*)  (ws + 59200000);                      //    200,000
    int*   offs  = (int*)  (ws + 59400000);                      //    200,064 (padded)
    int*   esort = (int*)  (ws + 59600128);                      //  3,200,000
    unsigned short* wpc = (unsigned short*)(ws + 62800128);      //  4*16KB
    unsigned short* wpt = (unsigned short*)(ws + 62865664);      // 16*16KB
    unsigned short* wpr = (unsigned short*)(ws + 63127808);      // 16*16KB
    unsigned short* wp0 = (unsigned short*)(ws + 63389952);      //  2*16KB
    unsigned short* wp1 = (unsigned short*)(ws + 63422720);      //  8*16KB
    if (ws_size < 63553792ull) return;                           // end of layout

    float* outh = (float*)d_out;                       // N*256 final h
    float4* atto = (float4*)(outh + (size_t)NN * 256); // E*4 att region

    // weight packing + cnt zeroing (single dispatch)
    pack_all_w<<<233, 256, 0, stream>>>(Wc, Wt, Wr, W0, W1,
                                        wpc, wpt, wpr, wp0, wp1, cnt);

    // trilinear fusion + inline layer-0 feat GEMM (featb/el/er out)
    fusion_mfma<<<NG, 256, 0, stream>>>(hc, ht, hr, wpc, wpt, wpr, wp0,
                                        Wc, Wt, Wr, fw, fb, al0, ar0,
                                        featb, el, er);

    // CSR by dst
    hist_kernel<<<(EE + 255) / 256, 256, 0, stream>>>(dst, cnt);
    scan_kernel<<<1, 1024, 0, stream>>>(cnt, offs);
    scatter_kernel<<<(EE + 255) / 256, 256, 0, stream>>>(dst, offs, cnt, esort);

    // GAT layer 0: softmax+agg in-register; bf16 h1b out
    gat_agg<0, 0, 1, 0><<<(NN * 64 + 255) / 256, 256, 0, stream>>>(
        esort, src, offs, featb, el, er, nullptr, b0, nullptr, h1b, nullptr);

    // GAT layer 1: feat + el/er fused; residual from bf16 h1b; f32 out + att
    gemm_reg<256><<<NG, 256, 0, stream>>>(h1b, wp1, al1, ar1, featb, el, er);
    gat_agg<1, 1, 0, 1><<<(NN * 64 + 255) / 256, 256, 0, stream>>>(
        esort, src, offs, featb, el, er, h1b, b1, outh, nullptr, atto);
}